// Round 1
// baseline (1676.419 us; speedup 1.0000x reference)
//
#include <hip/hip_runtime.h>
#include <hip/hip_bf16.h>
#include <cstdint>

// ---------------- problem constants ----------------
constexpr int BATCH = 8;
constexpr int NL = 5;
constexpr int CNTS[5] = {196608, 49152, 12288, 3072, 768};
constexpr int LOFF[5] = {0, 196608, 245760, 258048, 261120};
constexpr int PERB  = 261888;               // candidates per batch
constexpr int TOTC  = BATCH * PERB;         // 2,095,104
constexpr int PREK[5]  = {2000, 2000, 2000, 2000, 768};
constexpr int POSTK[5] = {1000, 1000, 1000, 1000, 768};
constexpr int COFF[5]  = {0, 1000, 2000, 3000, 4000};
constexpr int CONCATN  = 4768;
constexpr int SELSTRIDE = 2048;             // padded per-(b,l) selection stride
constexpr int CANDCAP   = 8192;             // candidate capacity for threshold-bin select
constexpr int MASKROWS  = 2000;
constexpr int MASKW     = 32;               // u64 words per mask row
constexpr int ROWS_PER_BATCH = 4 * 2000 + 768;  // 8768
constexpr float IOU_THR = 0.7f;
constexpr float CLIPV = 4.135166556742356f; // log(1000/16)

struct Ptrs {
    const float* bx[5];
    const float* sc[5];
    const float* an[5];
    const float* img;
};

// ---------------- helpers ----------------
__device__ __forceinline__ void bitonic_desc(unsigned long long* k, int N, int tid, int nt) {
    for (int kk = 2; kk <= N; kk <<= 1) {
        for (int j = kk >> 1; j > 0; j >>= 1) {
            __syncthreads();
            for (int i = tid; i < N; i += nt) {
                int ixj = i ^ j;
                if (ixj > i) {
                    bool up = ((i & kk) == 0);
                    unsigned long long a = k[i], b = k[ixj];
                    if ((a < b) == up) { k[i] = b; k[ixj] = a; }
                }
            }
        }
    }
    __syncthreads();
}

__device__ __forceinline__ unsigned long long shfl_u64(unsigned long long v, int src) {
    unsigned int lo = (unsigned int)v;
    unsigned int hi = (unsigned int)(v >> 32);
    lo = __shfl(lo, src);
    hi = __shfl(hi, src);
    return ((unsigned long long)hi << 32) | lo;
}

// ---------------- 1) decode + sigmoid + clip + histogram ----------------
__global__ void k_decode(Ptrs p, float4* __restrict__ dboxes, float* __restrict__ dscores,
                         unsigned int* __restrict__ hist) {
#pragma clang fp contract(off)
    int g = blockIdx.x * blockDim.x + threadIdx.x;
    if (g >= TOTC) return;
    int b = g / PERB;
    int r = g - b * PERB;
    int li;
    if      (r < LOFF[1]) li = 0;
    else if (r < LOFF[2]) li = 1;
    else if (r < LOFF[3]) li = 2;
    else if (r < LOFF[4]) li = 3;
    else                  li = 4;
    int i = r - LOFF[li];
    int n = CNTS[li];

    const float4 e = reinterpret_cast<const float4*>(p.bx[li])[(size_t)b * n + i];
    const float4 a = reinterpret_cast<const float4*>(p.an[li])[(size_t)b * n + i];
    float s = p.sc[li][(size_t)b * n + i];
    float hmax = p.img[b * 2 + 0];
    float wmax = p.img[b * 2 + 1];

    float dy = e.x, dx = e.y;
    float dh = fminf(e.z, CLIPV), dw = fminf(e.w, CLIPV);
    float ah = a.z - a.x, aw = a.w - a.y;
    float ayc = a.x + 0.5f * ah, axc = a.y + 0.5f * aw;
    float yc = dy * ah + ayc, xc = dx * aw + axc;
    float h = expf(dh) * ah, w = expf(dw) * aw;
    float y0 = yc - 0.5f * h, x0 = xc - 0.5f * w;
    float y1 = yc + 0.5f * h, x1 = xc + 0.5f * w;
    y0 = fminf(fmaxf(y0, 0.f), hmax);
    x0 = fminf(fmaxf(x0, 0.f), wmax);
    y1 = fminf(fmaxf(y1, 0.f), hmax);
    x1 = fminf(fmaxf(x1, 0.f), wmax);

    float sig = 1.0f / (1.0f + expf(-s));

    dboxes[g] = make_float4(y0, x0, y1, x1);
    dscores[g] = sig;

    unsigned int bits = __float_as_uint(sig);  // sig > 0 -> bits monotone in value
    int bl = b * NL + li;
    atomicAdd(&hist[(size_t)bl * 65536 + (bits >> 16)], 1u);
}

// ---------------- 2) find threshold bin per (b,l) ----------------
__global__ void k_findbin(const unsigned int* __restrict__ hist, int* __restrict__ T) {
    int bl = blockIdx.x;
    int li = bl % NL;
    unsigned int K = (unsigned int)PREK[li];
    __shared__ unsigned int csum[256];
    const unsigned int* h = hist + (size_t)bl * 65536;
    int tid = threadIdx.x;  // 256 threads
    unsigned int s = 0;
    for (int k = 0; k < 256; ++k) s += h[tid * 256 + k];
    csum[tid] = s;
    __syncthreads();
    if (tid == 0) {
        unsigned int cum = 0;
        int t = 0;
        for (int c = 255; c >= 0; --c) {
            if (cum + csum[c] >= K) {
                for (int bin = c * 256 + 255; bin >= c * 256; --bin) {
                    cum += h[bin];
                    if (cum >= K) { t = bin; break; }
                }
                break;
            }
            cum += csum[c];
        }
        T[bl] = t;
    }
}

// ---------------- 3) compact candidates >= threshold bin ----------------
__global__ void k_compact(const float* __restrict__ dscores, const int* __restrict__ T,
                          unsigned long long* __restrict__ cand, unsigned int* __restrict__ cnt) {
    int g = blockIdx.x * blockDim.x + threadIdx.x;
    if (g >= TOTC) return;
    int b = g / PERB;
    int r = g - b * PERB;
    int li;
    if      (r < LOFF[1]) li = 0;
    else if (r < LOFF[2]) li = 1;
    else if (r < LOFF[3]) li = 2;
    else if (r < LOFF[4]) li = 3;
    else                  li = 4;
    int i = r - LOFF[li];
    int bl = b * NL + li;

    unsigned int bits = __float_as_uint(dscores[g]);
    if ((int)(bits >> 16) >= T[bl]) {
        unsigned int pos = atomicAdd(&cnt[bl], 1u);
        if (pos < CANDCAP)
            cand[(size_t)bl * CANDCAP + pos] =
                ((unsigned long long)bits << 32) | (unsigned long long)(0xFFFFFFFFu - (unsigned int)i);
    }
}

// ---------------- 4) sort selected, gather top-K sorted boxes ----------------
__global__ __launch_bounds__(1024) void k_sortsel(const unsigned long long* __restrict__ cand,
                                                  const unsigned int* __restrict__ cnt,
                                                  const float4* __restrict__ dboxes,
                                                  float4* __restrict__ selb, float* __restrict__ sels) {
    __shared__ unsigned long long keys[CANDCAP];  // 64 KiB
    int bl = blockIdx.x;
    int tid = threadIdx.x;
    int b = bl / NL, li = bl % NL;
    int K = PREK[li];
    int n = min((int)cnt[bl], CANDCAP);
    for (int i = tid; i < CANDCAP; i += 1024)
        keys[i] = (i < n) ? cand[(size_t)bl * CANDCAP + i] : 0ull;
    bitonic_desc(keys, CANDCAP, tid, 1024);
    size_t seg = (size_t)b * PERB + LOFF[li];
    for (int r = tid; r < K; r += 1024) {
        unsigned long long kk = keys[r];
        unsigned int idx = 0xFFFFFFFFu - (unsigned int)(kk & 0xFFFFFFFFull);
        sels[(size_t)bl * SELSTRIDE + r] = __uint_as_float((unsigned int)(kk >> 32));
        selb[(size_t)bl * SELSTRIDE + r] = dboxes[seg + idx];
    }
}

// ---------------- 5) build triangular suppression bitmask ----------------
__global__ void k_mask(const float4* __restrict__ selb, unsigned long long* __restrict__ mask) {
#pragma clang fp contract(off)
    int rg = blockIdx.x;
    int b = rg / ROWS_PER_BATCH;
    int rem = rg - b * ROWS_PER_BATCH;
    int li, i;
    if (rem < 8000) { li = rem / 2000; i = rem - li * 2000; }
    else            { li = 4; i = rem - 8000; }
    int bl = b * NL + li;
    int K = PREK[li];
    const float4* bb = selb + (size_t)bl * SELSTRIDE;
    float4 bi = bb[i];
    float ai = (bi.z - bi.x) * (bi.w - bi.y);
    int tid = threadIdx.x;  // 256
    unsigned long long* mrow = mask + ((size_t)bl * MASKROWS + i) * MASKW;
    for (int cb = (i >> 6) << 6; cb < K; cb += 256) {
        int c = cb + tid;
        bool sup = false;
        if (c > i && c < K) {
            float4 bj = bb[c];
            float aj = (bj.z - bj.x) * (bj.w - bj.y);
            float iy = fmaxf(0.f, fminf(bi.z, bj.z) - fmaxf(bi.x, bj.x));
            float ix = fmaxf(0.f, fminf(bi.w, bj.w) - fmaxf(bi.y, bj.y));
            float inter = iy * ix;
            float iou = inter / (ai + aj - inter + 1e-8f);
            sup = iou > IOU_THR;
        }
        unsigned long long bal = __ballot(sup);
        int wb = cb + (tid & ~63);  // wave's base column
        if ((tid & 63) == 0 && wb < K) mrow[wb >> 6] = bal;
    }
}

// ---------------- 6) greedy NMS scan (1 wave per (b,l)) ----------------
__global__ __launch_bounds__(64) void k_scan(const unsigned long long* __restrict__ mask,
                                             unsigned long long* __restrict__ kept) {
    int bl = blockIdx.x;
    int li = bl % NL;
    int K = PREK[li];
    int W = (K + 63) >> 6;
    int lane = threadIdx.x;
    bool act = lane < W;
    const unsigned long long* m = mask + (size_t)bl * MASKROWS * MASKW + lane;
    unsigned long long removed = 0;
    unsigned long long buf[8];
#pragma unroll
    for (int d = 0; d < 8; ++d) buf[d] = act ? m[(size_t)d * MASKW] : 0ull;
    for (int i = 0; i < K; i += 8) {
#pragma unroll
        for (int d = 0; d < 8; ++d) {
            int ii = i + d;
            unsigned long long row = buf[d];
            int nr = ii + 8;
            buf[d] = (act && nr < K) ? m[(size_t)nr * MASKW] : 0ull;  // prefetch 8 ahead
            unsigned long long rw = shfl_u64(removed, ii >> 6);
            bool keptb = ((rw >> (ii & 63)) & 1ull) == 0ull;
            if (keptb && lane >= (ii >> 6)) removed |= row;  // low words of row are unwritten garbage
        }
    }
    if (act) {
        int remn = K - lane * 64;
        unsigned long long valid = (remn >= 64) ? ~0ull : ((1ull << remn) - 1ull);
        kept[bl * MASKW + lane] = (~removed) & valid;
    }
}

// ---------------- 7) per-level output: compact kept, zero-pad, concat ----------------
__global__ void k_lvlout(const unsigned long long* __restrict__ kept,
                         const float* __restrict__ sels, const float4* __restrict__ selb,
                         float* __restrict__ cscores, float4* __restrict__ cboxes) {
    int bl = blockIdx.x;
    int b = bl / NL, li = bl % NL;
    int K = PREK[li];
    int W = (K + 63) >> 6;
    int PK = POSTK[li];
    int tid = threadIdx.x;  // 256
    __shared__ unsigned long long kw[32];
    __shared__ int pref[33];
    if (tid < W) kw[tid] = kept[bl * MASKW + tid];
    __syncthreads();
    if (tid == 0) {
        int run = 0;
        for (int w = 0; w < W; ++w) { pref[w] = run; run += __popcll(kw[w]); }
        pref[W] = run;
    }
    __syncthreads();
    int total = pref[W];
    int nused = min(total, PK);
    float* cs = cscores + (size_t)b * CONCATN + COFF[li];
    float4* cbx = cboxes + (size_t)b * CONCATN + COFF[li];
    if (tid < W) {
        int rank = pref[tid];
        unsigned long long w64 = kw[tid];
        while (w64 != 0ull && rank < PK) {
            int j = __ffsll(w64) - 1;
            w64 &= (w64 - 1);
            int pidx = tid * 64 + j;
            cs[rank] = sels[(size_t)bl * SELSTRIDE + pidx];
            cbx[rank] = selb[(size_t)bl * SELSTRIDE + pidx];
            ++rank;
        }
    }
    for (int r = nused + tid; r < PK; r += 256) {
        cs[r] = 0.f;
        cbx[r] = make_float4(0.f, 0.f, 0.f, 0.f);
    }
}

// ---------------- 8) final per-batch top-1000 ----------------
__global__ __launch_bounds__(1024) void k_final(const float* __restrict__ cscores,
                                                const float4* __restrict__ cboxes,
                                                float* __restrict__ out) {
    __shared__ unsigned long long keys[8192];  // 64 KiB
    int b = blockIdx.x;
    int tid = threadIdx.x;
    const float* cs = cscores + (size_t)b * CONCATN;
    for (int i = tid; i < 8192; i += 1024)
        keys[i] = (i < CONCATN)
                      ? (((unsigned long long)__float_as_uint(cs[i]) << 32) |
                         (unsigned long long)(0xFFFFFFFFu - (unsigned int)i))
                      : 0ull;
    bitonic_desc(keys, 8192, tid, 1024);
    const float4* cbx = cboxes + (size_t)b * CONCATN;
    float4* ob = reinterpret_cast<float4*>(out) + (size_t)b * 1000;
    float* os = out + (size_t)BATCH * 1000 * 4 + (size_t)b * 1000;
    for (int r = tid; r < 1000; r += 1024) {
        unsigned long long kk = keys[r];
        unsigned int q = 0xFFFFFFFFu - (unsigned int)(kk & 0xFFFFFFFFull);
        ob[r] = cbx[q];
        os[r] = __uint_as_float((unsigned int)(kk >> 32));
    }
}

// ---------------- launcher ----------------
extern "C" void kernel_launch(void* const* d_in, const int* in_sizes, int n_in,
                              void* d_out, int out_size, void* d_ws, size_t ws_size,
                              hipStream_t stream) {
    Ptrs p;
    // setup_inputs() dict order: (boxes,scores,anchors) per level, then image_shape.
    // Defensive: disambiguate against grouped order via in_sizes[2]
    // (dict order -> anchors_l2 = 6,291,456; grouped -> boxes_l4 = 393,216).
    bool dict_order = (in_sizes[2] == 6291456);
    for (int l = 0; l < 5; ++l) {
        if (dict_order) {
            p.bx[l] = (const float*)d_in[3 * l + 0];
            p.sc[l] = (const float*)d_in[3 * l + 1];
            p.an[l] = (const float*)d_in[3 * l + 2];
        } else {
            p.bx[l] = (const float*)d_in[l];
            p.sc[l] = (const float*)d_in[5 + l];
            p.an[l] = (const float*)d_in[10 + l];
        }
    }
    p.img = (const float*)d_in[15];

    char* ws = (char*)d_ws;
    size_t off = 0;
    auto walloc = [&](size_t sz) -> void* {
        void* r = ws + off;
        off = (off + sz + 255) & ~(size_t)255;
        return r;
    };
    float4* dboxes             = (float4*)walloc((size_t)TOTC * 16);
    float* dscores             = (float*)walloc((size_t)TOTC * 4);
    unsigned int* hist         = (unsigned int*)walloc((size_t)40 * 65536 * 4);
    unsigned int* cnt          = (unsigned int*)walloc(40 * 4);
    int* T                     = (int*)walloc(40 * 4);
    unsigned long long* cand   = (unsigned long long*)walloc((size_t)40 * CANDCAP * 8);
    float4* selb               = (float4*)walloc((size_t)40 * SELSTRIDE * 16);
    float* sels                = (float*)walloc((size_t)40 * SELSTRIDE * 4);
    unsigned long long* mask   = (unsigned long long*)walloc((size_t)40 * MASKROWS * MASKW * 8);
    unsigned long long* kept   = (unsigned long long*)walloc((size_t)40 * MASKW * 8);
    float* cscores             = (float*)walloc((size_t)BATCH * CONCATN * 4);
    float4* cboxes             = (float4*)walloc((size_t)BATCH * CONCATN * 16);
    (void)ws_size;

    hipMemsetAsync(hist, 0, (size_t)40 * 65536 * 4, stream);
    hipMemsetAsync(cnt, 0, 40 * 4, stream);

    k_decode<<<(TOTC + 255) / 256, 256, 0, stream>>>(p, dboxes, dscores, hist);
    k_findbin<<<40, 256, 0, stream>>>(hist, T);
    k_compact<<<(TOTC + 255) / 256, 256, 0, stream>>>(dscores, T, cand, cnt);
    k_sortsel<<<40, 1024, 0, stream>>>(cand, cnt, dboxes, selb, sels);
    k_mask<<<BATCH * ROWS_PER_BATCH, 256, 0, stream>>>(selb, mask);
    k_scan<<<40, 64, 0, stream>>>(mask, kept);
    k_lvlout<<<40, 256, 0, stream>>>(kept, sels, selb, cscores, cboxes);
    k_final<<<8, 1024, 0, stream>>>(cscores, cboxes, (float*)d_out);
}

// Round 2
// 1195.750 us; speedup vs baseline: 1.4020x; 1.4020x over previous
//
#include <hip/hip_runtime.h>
#include <hip/hip_bf16.h>
#include <cstdint>

// ---------------- problem constants ----------------
constexpr int BATCH = 8;
constexpr int NL = 5;
constexpr int CNTS[5] = {196608, 49152, 12288, 3072, 768};
constexpr int LOFF[5] = {0, 196608, 245760, 258048, 261120};
constexpr int PERB  = 261888;               // candidates per batch
constexpr int TOTC  = BATCH * PERB;         // 2,095,104
constexpr int PREK[5]  = {2000, 2000, 2000, 2000, 768};
constexpr int POSTK[5] = {1000, 1000, 1000, 1000, 768};
constexpr int COFF[5]  = {0, 1000, 2000, 3000, 4000};
constexpr int CONCATN  = 4768;
constexpr int SELSTRIDE = 2048;             // padded per-(b,l) selection stride
constexpr int CANDCAP   = 8192;             // candidate capacity for threshold-bin select
constexpr int MASKROWS  = 2000;
constexpr int MASKW     = 32;               // u64 words per mask row
constexpr int ROWS_PER_BATCH = 4 * 2000 + 768;  // 8768
constexpr float IOU_THR = 0.7f;
constexpr float CLIPV = 4.135166556742356f; // log(1000/16)

struct Ptrs {
    const float* bx[5];
    const float* sc[5];
    const float* an[5];
    const float* img;
};

// ---------------- helpers ----------------
__device__ __forceinline__ void bitonic_desc(unsigned long long* k, int N, int tid, int nt) {
    for (int kk = 2; kk <= N; kk <<= 1) {
        for (int j = kk >> 1; j > 0; j >>= 1) {
            __syncthreads();
            for (int i = tid; i < N; i += nt) {
                int ixj = i ^ j;
                if (ixj > i) {
                    bool up = ((i & kk) == 0);
                    unsigned long long a = k[i], b = k[ixj];
                    if ((a < b) == up) { k[i] = b; k[ixj] = a; }
                }
            }
        }
    }
    __syncthreads();
}

__device__ __forceinline__ unsigned long long shfl_u64(unsigned long long v, int src) {
    unsigned int lo = (unsigned int)v;
    unsigned int hi = (unsigned int)(v >> 32);
    lo = __shfl(lo, src);
    hi = __shfl(hi, src);
    return ((unsigned long long)hi << 32) | lo;
}

// ---------------- 1) decode + sigmoid + clip + histogram ----------------
__global__ void k_decode(Ptrs p, float4* __restrict__ dboxes, float* __restrict__ dscores,
                         unsigned int* __restrict__ hist) {
#pragma clang fp contract(off)
    int g = blockIdx.x * blockDim.x + threadIdx.x;
    if (g >= TOTC) return;
    int b = g / PERB;
    int r = g - b * PERB;
    int li;
    if      (r < LOFF[1]) li = 0;
    else if (r < LOFF[2]) li = 1;
    else if (r < LOFF[3]) li = 2;
    else if (r < LOFF[4]) li = 3;
    else                  li = 4;
    int i = r - LOFF[li];
    int n = CNTS[li];

    const float4 e = reinterpret_cast<const float4*>(p.bx[li])[(size_t)b * n + i];
    const float4 a = reinterpret_cast<const float4*>(p.an[li])[(size_t)b * n + i];
    float s = p.sc[li][(size_t)b * n + i];
    float hmax = p.img[b * 2 + 0];
    float wmax = p.img[b * 2 + 1];

    float dy = e.x, dx = e.y;
    float dh = fminf(e.z, CLIPV), dw = fminf(e.w, CLIPV);
    float ah = a.z - a.x, aw = a.w - a.y;
    float ayc = a.x + 0.5f * ah, axc = a.y + 0.5f * aw;
    float yc = dy * ah + ayc, xc = dx * aw + axc;
    float h = expf(dh) * ah, w = expf(dw) * aw;
    float y0 = yc - 0.5f * h, x0 = xc - 0.5f * w;
    float y1 = yc + 0.5f * h, x1 = xc + 0.5f * w;
    y0 = fminf(fmaxf(y0, 0.f), hmax);
    x0 = fminf(fmaxf(x0, 0.f), wmax);
    y1 = fminf(fmaxf(y1, 0.f), hmax);
    x1 = fminf(fmaxf(x1, 0.f), wmax);

    float sig = 1.0f / (1.0f + expf(-s));

    dboxes[g] = make_float4(y0, x0, y1, x1);
    dscores[g] = sig;

    unsigned int bits = __float_as_uint(sig);  // sig > 0 -> bits monotone in value
    int bl = b * NL + li;
    atomicAdd(&hist[(size_t)bl * 65536 + (bits >> 16)], 1u);
}

// ---------------- 2) find threshold bin per (b,l) ----------------
__global__ void k_findbin(const unsigned int* __restrict__ hist, int* __restrict__ T) {
    int bl = blockIdx.x;
    int li = bl % NL;
    unsigned int K = (unsigned int)PREK[li];
    __shared__ unsigned int csum[256];
    const unsigned int* h = hist + (size_t)bl * 65536;
    int tid = threadIdx.x;  // 256 threads
    unsigned int s = 0;
    for (int k = 0; k < 256; ++k) s += h[tid * 256 + k];
    csum[tid] = s;
    __syncthreads();
    if (tid == 0) {
        unsigned int cum = 0;
        int t = 0;
        for (int c = 255; c >= 0; --c) {
            if (cum + csum[c] >= K) {
                for (int bin = c * 256 + 255; bin >= c * 256; --bin) {
                    cum += h[bin];
                    if (cum >= K) { t = bin; break; }
                }
                break;
            }
            cum += csum[c];
        }
        T[bl] = t;
    }
}

// ---------------- 3) compact candidates >= threshold bin ----------------
// Wave-aggregated atomic: all level/batch boundaries are 64-aligned, so every
// wave lies in exactly one (b,l) segment. One atomicAdd per wave (lane 0),
// lanes take base + prefix-popcount. Order within cand is irrelevant (sorted
// later), so this is semantics-preserving.
__global__ void k_compact(const float* __restrict__ dscores, const int* __restrict__ T,
                          unsigned long long* __restrict__ cand, unsigned int* __restrict__ cnt) {
    int g = blockIdx.x * blockDim.x + threadIdx.x;
    if (g >= TOTC) return;
    int b = g / PERB;
    int r = g - b * PERB;
    int li;
    if      (r < LOFF[1]) li = 0;
    else if (r < LOFF[2]) li = 1;
    else if (r < LOFF[3]) li = 2;
    else if (r < LOFF[4]) li = 3;
    else                  li = 4;
    int i = r - LOFF[li];
    int bl = b * NL + li;

    unsigned int bits = __float_as_uint(dscores[g]);
    bool pass = ((int)(bits >> 16) >= T[bl]);
    unsigned long long ball = __ballot(pass);
    int lane = threadIdx.x & 63;
    unsigned int base = 0;
    if (lane == 0 && ball != 0ull)
        base = atomicAdd(&cnt[bl], (unsigned int)__popcll(ball));
    base = __shfl((int)base, 0);
    if (pass) {
        unsigned int pos = base + (unsigned int)__popcll(ball & ((1ull << lane) - 1ull));
        if (pos < CANDCAP)
            cand[(size_t)bl * CANDCAP + pos] =
                ((unsigned long long)bits << 32) | (unsigned long long)(0xFFFFFFFFu - (unsigned int)i);
    }
}

// ---------------- 4) sort selected, gather top-K sorted boxes ----------------
__global__ __launch_bounds__(1024) void k_sortsel(const unsigned long long* __restrict__ cand,
                                                  const unsigned int* __restrict__ cnt,
                                                  const float4* __restrict__ dboxes,
                                                  float4* __restrict__ selb, float* __restrict__ sels) {
    __shared__ unsigned long long keys[CANDCAP];  // 64 KiB
    int bl = blockIdx.x;
    int tid = threadIdx.x;
    int b = bl / NL, li = bl % NL;
    int K = PREK[li];
    int n = min((int)cnt[bl], CANDCAP);
    for (int i = tid; i < CANDCAP; i += 1024)
        keys[i] = (i < n) ? cand[(size_t)bl * CANDCAP + i] : 0ull;
    bitonic_desc(keys, CANDCAP, tid, 1024);
    size_t seg = (size_t)b * PERB + LOFF[li];
    for (int r = tid; r < K; r += 1024) {
        unsigned long long kk = keys[r];
        unsigned int idx = 0xFFFFFFFFu - (unsigned int)(kk & 0xFFFFFFFFull);
        sels[(size_t)bl * SELSTRIDE + r] = __uint_as_float((unsigned int)(kk >> 32));
        selb[(size_t)bl * SELSTRIDE + r] = dboxes[seg + idx];
    }
}

// ---------------- 5) build triangular suppression bitmask ----------------
__global__ void k_mask(const float4* __restrict__ selb, unsigned long long* __restrict__ mask) {
#pragma clang fp contract(off)
    int rg = blockIdx.x;
    int b = rg / ROWS_PER_BATCH;
    int rem = rg - b * ROWS_PER_BATCH;
    int li, i;
    if (rem < 8000) { li = rem / 2000; i = rem - li * 2000; }
    else            { li = 4; i = rem - 8000; }
    int bl = b * NL + li;
    int K = PREK[li];
    const float4* bb = selb + (size_t)bl * SELSTRIDE;
    float4 bi = bb[i];
    float ai = (bi.z - bi.x) * (bi.w - bi.y);
    int tid = threadIdx.x;  // 256
    unsigned long long* mrow = mask + ((size_t)bl * MASKROWS + i) * MASKW;
    for (int cb = (i >> 6) << 6; cb < K; cb += 256) {
        int c = cb + tid;
        bool sup = false;
        if (c > i && c < K) {
            float4 bj = bb[c];
            float aj = (bj.z - bj.x) * (bj.w - bj.y);
            float iy = fmaxf(0.f, fminf(bi.z, bj.z) - fmaxf(bi.x, bj.x));
            float ix = fmaxf(0.f, fminf(bi.w, bj.w) - fmaxf(bi.y, bj.y));
            float inter = iy * ix;
            float iou = inter / (ai + aj - inter + 1e-8f);
            sup = iou > IOU_THR;
        }
        unsigned long long bal = __ballot(sup);
        int wb = cb + (tid & ~63);  // wave's base column
        if ((tid & 63) == 0 && wb < K) mrow[wb >> 6] = bal;
    }
}

// ---------------- 6) greedy NMS scan (1 wave per (b,l)) ----------------
__global__ __launch_bounds__(64) void k_scan(const unsigned long long* __restrict__ mask,
                                             unsigned long long* __restrict__ kept) {
    int bl = blockIdx.x;
    int li = bl % NL;
    int K = PREK[li];
    int W = (K + 63) >> 6;
    int lane = threadIdx.x;
    bool act = lane < W;
    const unsigned long long* m = mask + (size_t)bl * MASKROWS * MASKW + lane;
    unsigned long long removed = 0;
    unsigned long long buf[8];
#pragma unroll
    for (int d = 0; d < 8; ++d) buf[d] = act ? m[(size_t)d * MASKW] : 0ull;
    for (int i = 0; i < K; i += 8) {
#pragma unroll
        for (int d = 0; d < 8; ++d) {
            int ii = i + d;
            unsigned long long row = buf[d];
            int nr = ii + 8;
            buf[d] = (act && nr < K) ? m[(size_t)nr * MASKW] : 0ull;  // prefetch 8 ahead
            unsigned long long rw = shfl_u64(removed, ii >> 6);
            bool keptb = ((rw >> (ii & 63)) & 1ull) == 0ull;
            if (keptb && lane >= (ii >> 6)) removed |= row;  // low words of row are unwritten garbage
        }
    }
    if (act) {
        int remn = K - lane * 64;
        unsigned long long valid = (remn >= 64) ? ~0ull : ((1ull << remn) - 1ull);
        kept[bl * MASKW + lane] = (~removed) & valid;
    }
}

// ---------------- 7) per-level output: compact kept, zero-pad, concat ----------------
__global__ void k_lvlout(const unsigned long long* __restrict__ kept,
                         const float* __restrict__ sels, const float4* __restrict__ selb,
                         float* __restrict__ cscores, float4* __restrict__ cboxes) {
    int bl = blockIdx.x;
    int b = bl / NL, li = bl % NL;
    int K = PREK[li];
    int W = (K + 63) >> 6;
    int PK = POSTK[li];
    int tid = threadIdx.x;  // 256
    __shared__ unsigned long long kw[32];
    __shared__ int pref[33];
    if (tid < W) kw[tid] = kept[bl * MASKW + tid];
    __syncthreads();
    if (tid == 0) {
        int run = 0;
        for (int w = 0; w < W; ++w) { pref[w] = run; run += __popcll(kw[w]); }
        pref[W] = run;
    }
    __syncthreads();
    int total = pref[W];
    int nused = min(total, PK);
    float* cs = cscores + (size_t)b * CONCATN + COFF[li];
    float4* cbx = cboxes + (size_t)b * CONCATN + COFF[li];
    if (tid < W) {
        int rank = pref[tid];
        unsigned long long w64 = kw[tid];
        while (w64 != 0ull && rank < PK) {
            int j = __ffsll(w64) - 1;
            w64 &= (w64 - 1);
            int pidx = tid * 64 + j;
            cs[rank] = sels[(size_t)bl * SELSTRIDE + pidx];
            cbx[rank] = selb[(size_t)bl * SELSTRIDE + pidx];
            ++rank;
        }
    }
    for (int r = nused + tid; r < PK; r += 256) {
        cs[r] = 0.f;
        cbx[r] = make_float4(0.f, 0.f, 0.f, 0.f);
    }
}

// ---------------- 8) final per-batch top-1000 ----------------
__global__ __launch_bounds__(1024) void k_final(const float* __restrict__ cscores,
                                                const float4* __restrict__ cboxes,
                                                float* __restrict__ out) {
    __shared__ unsigned long long keys[8192];  // 64 KiB
    int b = blockIdx.x;
    int tid = threadIdx.x;
    const float* cs = cscores + (size_t)b * CONCATN;
    for (int i = tid; i < 8192; i += 1024)
        keys[i] = (i < CONCATN)
                      ? (((unsigned long long)__float_as_uint(cs[i]) << 32) |
                         (unsigned long long)(0xFFFFFFFFu - (unsigned int)i))
                      : 0ull;
    bitonic_desc(keys, 8192, tid, 1024);
    const float4* cbx = cboxes + (size_t)b * CONCATN;
    float4* ob = reinterpret_cast<float4*>(out) + (size_t)b * 1000;
    float* os = out + (size_t)BATCH * 1000 * 4 + (size_t)b * 1000;
    for (int r = tid; r < 1000; r += 1024) {
        unsigned long long kk = keys[r];
        unsigned int q = 0xFFFFFFFFu - (unsigned int)(kk & 0xFFFFFFFFull);
        ob[r] = cbx[q];
        os[r] = __uint_as_float((unsigned int)(kk >> 32));
    }
}

// ---------------- launcher ----------------
extern "C" void kernel_launch(void* const* d_in, const int* in_sizes, int n_in,
                              void* d_out, int out_size, void* d_ws, size_t ws_size,
                              hipStream_t stream) {
    Ptrs p;
    // setup_inputs() dict order: (boxes,scores,anchors) per level, then image_shape.
    // Defensive: disambiguate against grouped order via in_sizes[2]
    // (dict order -> anchors_l2 = 6,291,456; grouped -> boxes_l4 = 393,216).
    bool dict_order = (in_sizes[2] == 6291456);
    for (int l = 0; l < 5; ++l) {
        if (dict_order) {
            p.bx[l] = (const float*)d_in[3 * l + 0];
            p.sc[l] = (const float*)d_in[3 * l + 1];
            p.an[l] = (const float*)d_in[3 * l + 2];
        } else {
            p.bx[l] = (const float*)d_in[l];
            p.sc[l] = (const float*)d_in[5 + l];
            p.an[l] = (const float*)d_in[10 + l];
        }
    }
    p.img = (const float*)d_in[15];

    char* ws = (char*)d_ws;
    size_t off = 0;
    auto walloc = [&](size_t sz) -> void* {
        void* r = ws + off;
        off = (off + sz + 255) & ~(size_t)255;
        return r;
    };
    float4* dboxes             = (float4*)walloc((size_t)TOTC * 16);
    float* dscores             = (float*)walloc((size_t)TOTC * 4);
    unsigned int* hist         = (unsigned int*)walloc((size_t)40 * 65536 * 4);
    unsigned int* cnt          = (unsigned int*)walloc(40 * 4);
    int* T                     = (int*)walloc(40 * 4);
    unsigned long long* cand   = (unsigned long long*)walloc((size_t)40 * CANDCAP * 8);
    float4* selb               = (float4*)walloc((size_t)40 * SELSTRIDE * 16);
    float* sels                = (float*)walloc((size_t)40 * SELSTRIDE * 4);
    unsigned long long* mask   = (unsigned long long*)walloc((size_t)40 * MASKROWS * MASKW * 8);
    unsigned long long* kept   = (unsigned long long*)walloc((size_t)40 * MASKW * 8);
    float* cscores             = (float*)walloc((size_t)BATCH * CONCATN * 4);
    float4* cboxes             = (float4*)walloc((size_t)BATCH * CONCATN * 16);
    (void)ws_size;

    hipMemsetAsync(hist, 0, (size_t)40 * 65536 * 4, stream);
    hipMemsetAsync(cnt, 0, 40 * 4, stream);

    k_decode<<<(TOTC + 255) / 256, 256, 0, stream>>>(p, dboxes, dscores, hist);
    k_findbin<<<40, 256, 0, stream>>>(hist, T);
    k_compact<<<(TOTC + 255) / 256, 256, 0, stream>>>(dscores, T, cand, cnt);
    k_sortsel<<<40, 1024, 0, stream>>>(cand, cnt, dboxes, selb, sels);
    k_mask<<<BATCH * ROWS_PER_BATCH, 256, 0, stream>>>(selb, mask);
    k_scan<<<40, 64, 0, stream>>>(mask, kept);
    k_lvlout<<<40, 256, 0, stream>>>(kept, sels, selb, cscores, cboxes);
    k_final<<<8, 1024, 0, stream>>>(cscores, cboxes, (float*)d_out);
}

// Round 4
// 750.864 us; speedup vs baseline: 2.2327x; 1.5925x over previous
//
#include <hip/hip_runtime.h>
#include <hip/hip_bf16.h>
#include <cstdint>

// ---------------- problem constants ----------------
constexpr int BATCH = 8;
constexpr int NL = 5;
constexpr int CNTS[5] = {196608, 49152, 12288, 3072, 768};
constexpr int LOFF[5] = {0, 196608, 245760, 258048, 261120};
constexpr int PERB  = 261888;               // candidates per batch
constexpr int TOTC  = BATCH * PERB;         // 2,095,104
constexpr int PREK[5]  = {2000, 2000, 2000, 2000, 768};
constexpr int POSTK[5] = {1000, 1000, 1000, 1000, 768};
constexpr int COFF[5]  = {0, 1000, 2000, 3000, 4000};
constexpr int CONCATN  = 4768;
constexpr int SELSTRIDE = 2048;             // padded per-(b,l) selection stride
constexpr int CANDCAP   = 8192;             // candidate capacity for threshold-bin select
constexpr int NBINS     = 16384;            // score bins = float bits >> 16 (sig<=1.0 -> max 16256)
constexpr int MASKROWS  = 2000;
constexpr int MASKW     = 32;               // u64 words per mask row
constexpr int ROWS_PER_BATCH = 4 * 2000 + 768;  // 8768
constexpr float IOU_THR = 0.7f;
constexpr float CLIPV = 4.135166556742356f; // log(1000/16)

struct Ptrs {
    const float* bx[5];
    const float* sc[5];
    const float* an[5];
    const float* img;
};

// ---------------- helpers ----------------
__device__ __forceinline__ void bitonic_desc(unsigned long long* k, int N, int tid, int nt) {
    for (int kk = 2; kk <= N; kk <<= 1) {
        for (int j = kk >> 1; j > 0; j >>= 1) {
            __syncthreads();
            for (int i = tid; i < N; i += nt) {
                int ixj = i ^ j;
                if (ixj > i) {
                    bool up = ((i & kk) == 0);
                    unsigned long long a = k[i], b = k[ixj];
                    if ((a < b) == up) { k[i] = b; k[ixj] = a; }
                }
            }
        }
    }
    __syncthreads();
}

__device__ __forceinline__ unsigned long long shfl_u64(unsigned long long v, int src) {
    unsigned int lo = (unsigned int)v;
    unsigned int hi = (unsigned int)(v >> 32);
    lo = __shfl(lo, src);
    hi = __shfl(hi, src);
    return ((unsigned long long)hi << 32) | lo;
}

// ---------------- 1) score histogram (LDS-privatized) ----------------
// One block per 32K-element chunk of a (b,l) segment: 11 chunks/batch, 88 blocks.
// 16384 bins of (sigmoid bits >> 16), packed 2x16-bit per LDS word (32 KiB).
__global__ __launch_bounds__(1024) void k_hist(Ptrs p, unsigned int* __restrict__ hist) {
#pragma clang fp contract(off)
    __shared__ unsigned int h2[NBINS / 2];
    constexpr int CLI[11] = {0, 0, 0, 0, 0, 0, 1, 1, 2, 3, 4};
    constexpr int COF[11] = {0, 32768, 65536, 98304, 131072, 163840, 0, 24576, 0, 0, 0};
    constexpr int CLN[11] = {32768, 32768, 32768, 32768, 32768, 32768, 24576, 24576, 12288, 3072, 768};
    int blk = blockIdx.x;
    int b = blk / 11, c = blk % 11;
    int li = CLI[c], off = COF[c], len = CLN[c];
    int tid = threadIdx.x;
    for (int i = tid; i < NBINS / 2; i += 1024) h2[i] = 0;
    __syncthreads();
    const float* sp = p.sc[li] + (size_t)b * CNTS[li] + off;
    for (int i = tid; i < len; i += 1024) {
        float s = sp[i];
        float sig = 1.0f / (1.0f + expf(-s));
        unsigned int bin = __float_as_uint(sig) >> 16;
        atomicAdd(&h2[bin >> 1], 1u << ((bin & 1) << 4));
    }
    __syncthreads();
    unsigned int* H = hist + (size_t)(b * NL + li) * NBINS;
    for (int i = tid; i < NBINS / 2; i += 1024) {
        unsigned int v = h2[i];
        if (v & 0xFFFFu) atomicAdd(&H[2 * i], v & 0xFFFFu);
        if (v >> 16) atomicAdd(&H[2 * i + 1], v >> 16);
    }
}

// ---------------- 2) find threshold bin per (b,l) ----------------
__global__ void k_findbin(const unsigned int* __restrict__ hist, int* __restrict__ T) {
    int bl = blockIdx.x;
    int li = bl % NL;
    unsigned int K = (unsigned int)PREK[li];
    __shared__ unsigned int csum[256];
    const unsigned int* h = hist + (size_t)bl * NBINS;
    int tid = threadIdx.x;  // 256 threads, 64 bins each
    unsigned int s = 0;
    for (int k = 0; k < 64; ++k) s += h[tid * 64 + k];
    csum[tid] = s;
    __syncthreads();
    if (tid == 0) {
        unsigned int cum = 0;
        int t = 0;
        for (int c = 255; c >= 0; --c) {
            if (cum + csum[c] >= K) {
                for (int bin = c * 64 + 63; bin >= c * 64; --bin) {
                    cum += h[bin];
                    if (cum >= K) { t = bin; break; }
                }
                break;
            }
            cum += csum[c];
        }
        T[bl] = t;
    }
}

// ---------------- 3) compact candidates >= threshold bin ----------------
// Recomputes sigmoid from raw scores (bit-identical to k_hist). Wave-aggregated
// atomic: all level/batch boundaries are 64-aligned, so every wave lies in one
// (b,l) segment. Order within cand is irrelevant (sorted later).
__global__ void k_compact(Ptrs p, const int* __restrict__ T,
                          unsigned long long* __restrict__ cand, unsigned int* __restrict__ cnt) {
#pragma clang fp contract(off)
    int g = blockIdx.x * blockDim.x + threadIdx.x;
    if (g >= TOTC) return;
    int b = g / PERB;
    int r = g - b * PERB;
    int li;
    if      (r < LOFF[1]) li = 0;
    else if (r < LOFF[2]) li = 1;
    else if (r < LOFF[3]) li = 2;
    else if (r < LOFF[4]) li = 3;
    else                  li = 4;
    int i = r - LOFF[li];
    int bl = b * NL + li;

    float s = p.sc[li][(size_t)b * CNTS[li] + i];
    float sig = 1.0f / (1.0f + expf(-s));
    unsigned int bits = __float_as_uint(sig);
    bool pass = ((int)(bits >> 16) >= T[bl]);
    unsigned long long ball = __ballot(pass);
    int lane = threadIdx.x & 63;
    unsigned int base = 0;
    if (lane == 0 && ball != 0ull)
        base = atomicAdd(&cnt[bl], (unsigned int)__popcll(ball));
    base = __shfl((int)base, 0);
    if (pass) {
        unsigned int pos = base + (unsigned int)__popcll(ball & ((1ull << lane) - 1ull));
        if (pos < CANDCAP)
            cand[(size_t)bl * CANDCAP + pos] =
                ((unsigned long long)bits << 32) | (unsigned long long)(0xFFFFFFFFu - (unsigned int)i);
    }
}

// ---------------- 4) sort selected, decode+clip only the top-K boxes ----------------
__global__ __launch_bounds__(1024) void k_sortsel(const unsigned long long* __restrict__ cand,
                                                  const unsigned int* __restrict__ cnt, Ptrs p,
                                                  float4* __restrict__ selb, float* __restrict__ sels) {
#pragma clang fp contract(off)
    __shared__ unsigned long long keys[CANDCAP];  // 64 KiB
    int bl = blockIdx.x;
    int tid = threadIdx.x;
    int b = bl / NL, li = bl % NL;
    int K = PREK[li];
    int n = min((int)cnt[bl], CANDCAP);
    int N = 1024;
    while (N < n) N <<= 1;
    for (int i = tid; i < N; i += 1024)
        keys[i] = (i < n) ? cand[(size_t)bl * CANDCAP + i] : 0ull;
    bitonic_desc(keys, N, tid, 1024);

    int nn = CNTS[li];
    float hmax = p.img[b * 2 + 0];
    float wmax = p.img[b * 2 + 1];
    const float4* bxp = reinterpret_cast<const float4*>(p.bx[li]) + (size_t)b * nn;
    const float4* anp = reinterpret_cast<const float4*>(p.an[li]) + (size_t)b * nn;
    for (int r = tid; r < K; r += 1024) {
        unsigned long long kk = keys[r];
        unsigned int idx = 0xFFFFFFFFu - (unsigned int)(kk & 0xFFFFFFFFull);
        const float4 e = bxp[idx];
        const float4 a = anp[idx];
        float dy = e.x, dx = e.y;
        float dh = fminf(e.z, CLIPV), dw = fminf(e.w, CLIPV);
        float ah = a.z - a.x, aw = a.w - a.y;
        float ayc = a.x + 0.5f * ah, axc = a.y + 0.5f * aw;
        float yc = dy * ah + ayc, xc = dx * aw + axc;
        float h = expf(dh) * ah, w = expf(dw) * aw;
        float y0 = yc - 0.5f * h, x0 = xc - 0.5f * w;
        float y1 = yc + 0.5f * h, x1 = xc + 0.5f * w;
        y0 = fminf(fmaxf(y0, 0.f), hmax);
        x0 = fminf(fmaxf(x0, 0.f), wmax);
        y1 = fminf(fmaxf(y1, 0.f), hmax);
        x1 = fminf(fmaxf(x1, 0.f), wmax);
        sels[(size_t)bl * SELSTRIDE + r] = __uint_as_float((unsigned int)(kk >> 32));
        selb[(size_t)bl * SELSTRIDE + r] = make_float4(y0, x0, y1, x1);
    }
}

// ---------------- 5) build triangular suppression bitmask ----------------
__global__ void k_mask(const float4* __restrict__ selb, unsigned long long* __restrict__ mask) {
#pragma clang fp contract(off)
    int rg = blockIdx.x;
    int b = rg / ROWS_PER_BATCH;
    int rem = rg - b * ROWS_PER_BATCH;
    int li, i;
    if (rem < 8000) { li = rem / 2000; i = rem - li * 2000; }
    else            { li = 4; i = rem - 8000; }
    int bl = b * NL + li;
    int K = PREK[li];
    const float4* bb = selb + (size_t)bl * SELSTRIDE;
    float4 bi = bb[i];
    float ai = (bi.z - bi.x) * (bi.w - bi.y);
    int tid = threadIdx.x;  // 256
    unsigned long long* mrow = mask + ((size_t)bl * MASKROWS + i) * MASKW;
    for (int cb = (i >> 6) << 6; cb < K; cb += 256) {
        int c = cb + tid;
        bool sup = false;
        if (c > i && c < K) {
            float4 bj = bb[c];
            float aj = (bj.z - bj.x) * (bj.w - bj.y);
            float iy = fmaxf(0.f, fminf(bi.z, bj.z) - fmaxf(bi.x, bj.x));
            float ix = fmaxf(0.f, fminf(bi.w, bj.w) - fmaxf(bi.y, bj.y));
            float inter = iy * ix;
            float iou = inter / (ai + aj - inter + 1e-8f);
            sup = iou > IOU_THR;
        }
        unsigned long long bal = __ballot(sup);
        int wb = cb + (tid & ~63);  // wave's base column
        if ((tid & 63) == 0 && wb < K) mrow[wb >> 6] = bal;
    }
}

// ---------------- 6) greedy NMS scan (1 wave per (b,l)) ----------------
// Serial-chain optimization: `local` is a wave-uniform broadcast copy of the
// current 64-row group's removed-word. Per-row critical path is ~4 VALU ops;
// the row-data shuffle is off the chain (operates on prefetched data). One
// dependent shuffle per 64 rows. Prefetch depth 16 (rows are 256B apart).
__global__ __launch_bounds__(64) void k_scan(const unsigned long long* __restrict__ mask,
                                             unsigned long long* __restrict__ kept) {
    int bl = blockIdx.x;
    int li = bl % NL;
    int K = PREK[li];         // multiple of 16
    int W = (K + 63) >> 6;
    int lane = threadIdx.x;
    bool act = lane < W;
    const unsigned long long* m = mask + (size_t)bl * MASKROWS * MASKW + lane;
    unsigned long long removed = 0;
    constexpr int D = 16;
    unsigned long long buf[D];
#pragma unroll
    for (int d = 0; d < D; ++d) buf[d] = act ? m[(size_t)d * MASKW] : 0ull;
    unsigned long long local = 0;
    for (int i = 0; i < K; i += D) {
#pragma unroll
        for (int d = 0; d < D; ++d) {
            int ii = i + d;
            unsigned long long row = buf[d];
            int nr = ii + D;
            buf[d] = (act && nr < K) ? m[(size_t)nr * MASKW] : 0ull;  // prefetch D ahead
            int g = ii >> 6;
            if ((ii & 63) == 0) local = shfl_u64(removed, g);  // group start: resync broadcast copy
            unsigned long long rg = shfl_u64(row, g);          // row's word g (off critical path)
            bool keptb = ((local >> (ii & 63)) & 1ull) == 0ull;  // wave-uniform
            unsigned long long sel = keptb ? ~0ull : 0ull;
            if (lane >= g) removed |= row & sel;  // low words of row are unwritten garbage
            local |= rg & sel;
        }
    }
    if (act) {
        int remn = K - lane * 64;
        unsigned long long valid = (remn >= 64) ? ~0ull : ((1ull << remn) - 1ull);
        kept[bl * MASKW + lane] = (~removed) & valid;
    }
}

// ---------------- 7) per-level output: compact kept, zero-pad, concat ----------------
__global__ void k_lvlout(const unsigned long long* __restrict__ kept,
                         const float* __restrict__ sels, const float4* __restrict__ selb,
                         float* __restrict__ cscores, float4* __restrict__ cboxes) {
    int bl = blockIdx.x;
    int b = bl / NL, li = bl % NL;
    int K = PREK[li];
    int W = (K + 63) >> 6;
    int PK = POSTK[li];
    int tid = threadIdx.x;  // 256
    __shared__ unsigned long long kw[32];
    __shared__ int pref[33];
    if (tid < W) kw[tid] = kept[bl * MASKW + tid];
    __syncthreads();
    if (tid == 0) {
        int run = 0;
        for (int w = 0; w < W; ++w) { pref[w] = run; run += __popcll(kw[w]); }
        pref[W] = run;
    }
    __syncthreads();
    int total = pref[W];
    int nused = min(total, PK);
    float* cs = cscores + (size_t)b * CONCATN + COFF[li];
    float4* cbx = cboxes + (size_t)b * CONCATN + COFF[li];
    if (tid < W) {
        int rank = pref[tid];
        unsigned long long w64 = kw[tid];
        while (w64 != 0ull && rank < PK) {
            int j = __ffsll(w64) - 1;
            w64 &= (w64 - 1);
            int pidx = tid * 64 + j;
            cs[rank] = sels[(size_t)bl * SELSTRIDE + pidx];
            cbx[rank] = selb[(size_t)bl * SELSTRIDE + pidx];
            ++rank;
        }
    }
    for (int r = nused + tid; r < PK; r += 256) {
        cs[r] = 0.f;
        cbx[r] = make_float4(0.f, 0.f, 0.f, 0.f);
    }
}

// ---------------- 8) final per-batch top-1000 ----------------
__global__ __launch_bounds__(1024) void k_final(const float* __restrict__ cscores,
                                                const float4* __restrict__ cboxes,
                                                float* __restrict__ out) {
    __shared__ unsigned long long keys[8192];  // 64 KiB
    int b = blockIdx.x;
    int tid = threadIdx.x;
    const float* cs = cscores + (size_t)b * CONCATN;
    for (int i = tid; i < 8192; i += 1024)
        keys[i] = (i < CONCATN)
                      ? (((unsigned long long)__float_as_uint(cs[i]) << 32) |
                         (unsigned long long)(0xFFFFFFFFu - (unsigned int)i))
                      : 0ull;
    bitonic_desc(keys, 8192, tid, 1024);
    const float4* cbx = cboxes + (size_t)b * CONCATN;
    float4* ob = reinterpret_cast<float4*>(out) + (size_t)b * 1000;
    float* os = out + (size_t)BATCH * 1000 * 4 + (size_t)b * 1000;
    for (int r = tid; r < 1000; r += 1024) {
        unsigned long long kk = keys[r];
        unsigned int q = 0xFFFFFFFFu - (unsigned int)(kk & 0xFFFFFFFFull);
        ob[r] = cbx[q];
        os[r] = __uint_as_float((unsigned int)(kk >> 32));
    }
}

// ---------------- launcher ----------------
extern "C" void kernel_launch(void* const* d_in, const int* in_sizes, int n_in,
                              void* d_out, int out_size, void* d_ws, size_t ws_size,
                              hipStream_t stream) {
    Ptrs p;
    // setup_inputs() dict order: (boxes,scores,anchors) per level, then image_shape.
    bool dict_order = (in_sizes[2] == 6291456);
    for (int l = 0; l < 5; ++l) {
        if (dict_order) {
            p.bx[l] = (const float*)d_in[3 * l + 0];
            p.sc[l] = (const float*)d_in[3 * l + 1];
            p.an[l] = (const float*)d_in[3 * l + 2];
        } else {
            p.bx[l] = (const float*)d_in[l];
            p.sc[l] = (const float*)d_in[5 + l];
            p.an[l] = (const float*)d_in[10 + l];
        }
    }
    p.img = (const float*)d_in[15];

    char* ws = (char*)d_ws;
    size_t off = 0;
    auto walloc = [&](size_t sz) -> void* {
        void* r = ws + off;
        off = (off + sz + 255) & ~(size_t)255;
        return r;
    };
    unsigned int* hist         = (unsigned int*)walloc((size_t)40 * NBINS * 4);
    unsigned int* cnt          = (unsigned int*)walloc(40 * 4);
    int* T                     = (int*)walloc(40 * 4);
    unsigned long long* cand   = (unsigned long long*)walloc((size_t)40 * CANDCAP * 8);
    float4* selb               = (float4*)walloc((size_t)40 * SELSTRIDE * 16);
    float* sels                = (float*)walloc((size_t)40 * SELSTRIDE * 4);
    unsigned long long* mask   = (unsigned long long*)walloc((size_t)40 * MASKROWS * MASKW * 8);
    unsigned long long* kept   = (unsigned long long*)walloc((size_t)40 * MASKW * 8);
    float* cscores             = (float*)walloc((size_t)BATCH * CONCATN * 4);
    float4* cboxes             = (float4*)walloc((size_t)BATCH * CONCATN * 16);
    (void)ws_size;

    hipMemsetAsync(hist, 0, (size_t)40 * NBINS * 4, stream);
    hipMemsetAsync(cnt, 0, 40 * 4, stream);

    k_hist<<<BATCH * 11, 1024, 0, stream>>>(p, hist);
    k_findbin<<<40, 256, 0, stream>>>(hist, T);
    k_compact<<<(TOTC + 255) / 256, 256, 0, stream>>>(p, T, cand, cnt);
    k_sortsel<<<40, 1024, 0, stream>>>(cand, cnt, p, selb, sels);
    k_mask<<<BATCH * ROWS_PER_BATCH, 256, 0, stream>>>(selb, mask);
    k_scan<<<40, 64, 0, stream>>>(mask, kept);
    k_lvlout<<<40, 256, 0, stream>>>(kept, sels, selb, cscores, cboxes);
    k_final<<<8, 1024, 0, stream>>>(cscores, cboxes, (float*)d_out);
}

// Round 5
// 575.385 us; speedup vs baseline: 2.9136x; 1.3050x over previous
//
#include <hip/hip_runtime.h>
#include <hip/hip_bf16.h>
#include <cstdint>

// ---------------- problem constants ----------------
constexpr int BATCH = 8;
constexpr int NL = 5;
constexpr int CNTS[5] = {196608, 49152, 12288, 3072, 768};
constexpr int LOFF[5] = {0, 196608, 245760, 258048, 261120};
constexpr int PERB  = 261888;               // candidates per batch
constexpr int TOTC  = BATCH * PERB;         // 2,095,104
constexpr int PREK[5]  = {2000, 2000, 2000, 2000, 768};
constexpr int POSTK[5] = {1000, 1000, 1000, 1000, 768};
constexpr int COFF[5]  = {0, 1000, 2000, 3000, 4000};
constexpr int CONCATN  = 4768;
constexpr int SELSTRIDE = 2048;             // padded per-(b,l) selection stride
constexpr int CANDCAP   = 8192;             // total candidate capacity per (b,l)
constexpr int NREP      = 64;               // counter/region replicas per (b,l)
constexpr int REPCAP    = 512;              // slots per replica region
constexpr int NBINS     = 16384;            // score bins = float bits >> 16 (sig<=1.0 -> max 16256)
constexpr int MASKROWS  = 2000;
constexpr int MASKW     = 32;               // u64 words per mask row
constexpr int ROWS_PER_BATCH = 4 * 2000 + 768;  // 8768
constexpr float IOU_THR = 0.7f;
constexpr float CLIPV = 4.135166556742356f; // log(1000/16)

struct Ptrs {
    const float* bx[5];
    const float* sc[5];
    const float* an[5];
    const float* img;
};

// ---------------- helpers ----------------
__device__ __forceinline__ void bitonic_desc(unsigned long long* k, int N, int tid, int nt) {
    for (int kk = 2; kk <= N; kk <<= 1) {
        for (int j = kk >> 1; j > 0; j >>= 1) {
            __syncthreads();
            for (int i = tid; i < N; i += nt) {
                int ixj = i ^ j;
                if (ixj > i) {
                    bool up = ((i & kk) == 0);
                    unsigned long long a = k[i], b = k[ixj];
                    if ((a < b) == up) { k[i] = b; k[ixj] = a; }
                }
            }
        }
    }
    __syncthreads();
}

__device__ __forceinline__ unsigned long long shfl_u64(unsigned long long v, int src) {
    unsigned int lo = (unsigned int)v;
    unsigned int hi = (unsigned int)(v >> 32);
    lo = __shfl(lo, src);
    hi = __shfl(hi, src);
    return ((unsigned long long)hi << 32) | lo;
}

// ---------------- 1) score histogram (LDS-privatized) ----------------
// One block per 32K-element chunk of a (b,l) segment: 11 chunks/batch, 88 blocks.
// 16384 bins of (sigmoid bits >> 16), packed 2x16-bit per LDS word (32 KiB).
__global__ __launch_bounds__(1024) void k_hist(Ptrs p, unsigned int* __restrict__ hist) {
#pragma clang fp contract(off)
    __shared__ unsigned int h2[NBINS / 2];
    constexpr int CLI[11] = {0, 0, 0, 0, 0, 0, 1, 1, 2, 3, 4};
    constexpr int COF[11] = {0, 32768, 65536, 98304, 131072, 163840, 0, 24576, 0, 0, 0};
    constexpr int CLN[11] = {32768, 32768, 32768, 32768, 32768, 32768, 24576, 24576, 12288, 3072, 768};
    int blk = blockIdx.x;
    int b = blk / 11, c = blk % 11;
    int li = CLI[c], off = COF[c], len = CLN[c];
    int tid = threadIdx.x;
    for (int i = tid; i < NBINS / 2; i += 1024) h2[i] = 0;
    __syncthreads();
    const float* sp = p.sc[li] + (size_t)b * CNTS[li] + off;
    for (int i = tid; i < len; i += 1024) {
        float s = sp[i];
        float sig = 1.0f / (1.0f + expf(-s));
        unsigned int bin = __float_as_uint(sig) >> 16;
        atomicAdd(&h2[bin >> 1], 1u << ((bin & 1) << 4));
    }
    __syncthreads();
    unsigned int* H = hist + (size_t)(b * NL + li) * NBINS;
    for (int i = tid; i < NBINS / 2; i += 1024) {
        unsigned int v = h2[i];
        if (v & 0xFFFFu) atomicAdd(&H[2 * i], v & 0xFFFFu);
        if (v >> 16) atomicAdd(&H[2 * i + 1], v >> 16);
    }
}

// ---------------- 2) find threshold bin per (b,l) ----------------
__global__ void k_findbin(const unsigned int* __restrict__ hist, int* __restrict__ T) {
    int bl = blockIdx.x;
    int li = bl % NL;
    unsigned int K = (unsigned int)PREK[li];
    __shared__ unsigned int csum[256];
    const unsigned int* h = hist + (size_t)bl * NBINS;
    int tid = threadIdx.x;  // 256 threads, 64 bins each
    unsigned int s = 0;
    for (int k = 0; k < 64; ++k) s += h[tid * 64 + k];
    csum[tid] = s;
    __syncthreads();
    if (tid == 0) {
        unsigned int cum = 0;
        int t = 0;
        for (int c = 255; c >= 0; --c) {
            if (cum + csum[c] >= K) {
                for (int bin = c * 64 + 63; bin >= c * 64; --bin) {
                    cum += h[bin];
                    if (cum >= K) { t = bin; break; }
                }
                break;
            }
            cum += csum[c];
        }
        T[bl] = t;
    }
}

// ---------------- 3) compact candidates >= threshold bin ----------------
// Wave-aggregated atomic + 64x replicated counters: cntR[rep*64+bl] puts each
// replica set in its own 256B region, so the ~16K wave atomics spread across
// 64 independent cache lines instead of serializing on 3. Each replica owns a
// fixed 512-slot region of cand (expected ~33/replica; per-block max 256).
__global__ void k_compact(Ptrs p, const int* __restrict__ T,
                          unsigned long long* __restrict__ cand, unsigned int* __restrict__ cntR) {
#pragma clang fp contract(off)
    int g = blockIdx.x * blockDim.x + threadIdx.x;
    if (g >= TOTC) return;
    int b = g / PERB;
    int r = g - b * PERB;
    int li;
    if      (r < LOFF[1]) li = 0;
    else if (r < LOFF[2]) li = 1;
    else if (r < LOFF[3]) li = 2;
    else if (r < LOFF[4]) li = 3;
    else                  li = 4;
    int i = r - LOFF[li];
    int bl = b * NL + li;
    int rep = blockIdx.x & (NREP - 1);

    float s = p.sc[li][(size_t)b * CNTS[li] + i];
    float sig = 1.0f / (1.0f + expf(-s));
    unsigned int bits = __float_as_uint(sig);
    bool pass = ((int)(bits >> 16) >= T[bl]);
    unsigned long long ball = __ballot(pass);
    int lane = threadIdx.x & 63;
    unsigned int base = 0;
    if (lane == 0 && ball != 0ull)
        base = atomicAdd(&cntR[rep * 64 + bl], (unsigned int)__popcll(ball));
    base = __shfl((int)base, 0);
    if (pass) {
        unsigned int pos = base + (unsigned int)__popcll(ball & ((1ull << lane) - 1ull));
        if (pos < REPCAP)
            cand[((size_t)bl * NREP + rep) * REPCAP + pos] =
                ((unsigned long long)bits << 32) | (unsigned long long)(0xFFFFFFFFu - (unsigned int)i);
    }
}

// ---------------- 4) sort selected, decode+clip only the top-K boxes ----------------
__global__ __launch_bounds__(1024) void k_sortsel(const unsigned long long* __restrict__ cand,
                                                  const unsigned int* __restrict__ cntR, Ptrs p,
                                                  float4* __restrict__ selb, float* __restrict__ sels) {
#pragma clang fp contract(off)
    __shared__ unsigned long long keys[CANDCAP];  // 64 KiB
    __shared__ int pref[NREP + 1];
    int bl = blockIdx.x;
    int tid = threadIdx.x;
    int b = bl / NL, li = bl % NL;
    int K = PREK[li];
    if (tid == 0) {
        int run = 0;
        for (int rp = 0; rp < NREP; ++rp) {
            pref[rp] = run;
            int c = min((int)cntR[rp * 64 + bl], REPCAP);
            if (run + c > CANDCAP) c = CANDCAP - run;
            run += c;
        }
        pref[NREP] = run;
    }
    __syncthreads();
    int n = pref[NREP];
    int N = 1024;
    while (N < n) N <<= 1;
    for (int i = tid; i < N; i += 1024) keys[i] = 0ull;
    __syncthreads();
    for (int rp = 0; rp < NREP; ++rp) {
        int base = pref[rp], c = pref[rp + 1] - pref[rp];
        const unsigned long long* src = cand + ((size_t)bl * NREP + rp) * REPCAP;
        for (int j = tid; j < c; j += 1024) keys[base + j] = src[j];
    }
    bitonic_desc(keys, N, tid, 1024);

    int nn = CNTS[li];
    float hmax = p.img[b * 2 + 0];
    float wmax = p.img[b * 2 + 1];
    const float4* bxp = reinterpret_cast<const float4*>(p.bx[li]) + (size_t)b * nn;
    const float4* anp = reinterpret_cast<const float4*>(p.an[li]) + (size_t)b * nn;
    for (int r = tid; r < K; r += 1024) {
        unsigned long long kk = keys[r];
        unsigned int idx = 0xFFFFFFFFu - (unsigned int)(kk & 0xFFFFFFFFull);
        const float4 e = bxp[idx];
        const float4 a = anp[idx];
        float dy = e.x, dx = e.y;
        float dh = fminf(e.z, CLIPV), dw = fminf(e.w, CLIPV);
        float ah = a.z - a.x, aw = a.w - a.y;
        float ayc = a.x + 0.5f * ah, axc = a.y + 0.5f * aw;
        float yc = dy * ah + ayc, xc = dx * aw + axc;
        float h = expf(dh) * ah, w = expf(dw) * aw;
        float y0 = yc - 0.5f * h, x0 = xc - 0.5f * w;
        float y1 = yc + 0.5f * h, x1 = xc + 0.5f * w;
        y0 = fminf(fmaxf(y0, 0.f), hmax);
        x0 = fminf(fmaxf(x0, 0.f), wmax);
        y1 = fminf(fmaxf(y1, 0.f), hmax);
        x1 = fminf(fmaxf(x1, 0.f), wmax);
        sels[(size_t)bl * SELSTRIDE + r] = __uint_as_float((unsigned int)(kk >> 32));
        selb[(size_t)bl * SELSTRIDE + r] = make_float4(y0, x0, y1, x1);
    }
}

// ---------------- 5) build triangular suppression bitmask ----------------
__global__ void k_mask(const float4* __restrict__ selb, unsigned long long* __restrict__ mask) {
#pragma clang fp contract(off)
    int rg = blockIdx.x;
    int b = rg / ROWS_PER_BATCH;
    int rem = rg - b * ROWS_PER_BATCH;
    int li, i;
    if (rem < 8000) { li = rem / 2000; i = rem - li * 2000; }
    else            { li = 4; i = rem - 8000; }
    int bl = b * NL + li;
    int K = PREK[li];
    const float4* bb = selb + (size_t)bl * SELSTRIDE;
    float4 bi = bb[i];
    float ai = (bi.z - bi.x) * (bi.w - bi.y);
    int tid = threadIdx.x;  // 256
    unsigned long long* mrow = mask + ((size_t)bl * MASKROWS + i) * MASKW;
    for (int cb = (i >> 6) << 6; cb < K; cb += 256) {
        int c = cb + tid;
        bool sup = false;
        if (c > i && c < K) {
            float4 bj = bb[c];
            float aj = (bj.z - bj.x) * (bj.w - bj.y);
            float iy = fmaxf(0.f, fminf(bi.z, bj.z) - fmaxf(bi.x, bj.x));
            float ix = fmaxf(0.f, fminf(bi.w, bj.w) - fmaxf(bi.y, bj.y));
            float inter = iy * ix;
            float iou = inter / (ai + aj - inter + 1e-8f);
            sup = iou > IOU_THR;
        }
        unsigned long long bal = __ballot(sup);
        int wb = cb + (tid & ~63);  // wave's base column
        if ((tid & 63) == 0 && wb < K) mrow[wb >> 6] = bal;
    }
}

// ---------------- 6) greedy NMS scan (1 wave per (b,l)) ----------------
// Serial-chain optimization: `local` is a wave-uniform broadcast copy of the
// current 64-row group's removed-word. Per-row critical path is ~4 VALU ops;
// the row-data shuffle is off the chain (operates on prefetched data). One
// dependent shuffle per 64 rows. Prefetch depth 16 (rows are 256B apart).
__global__ __launch_bounds__(64) void k_scan(const unsigned long long* __restrict__ mask,
                                             unsigned long long* __restrict__ kept) {
    int bl = blockIdx.x;
    int li = bl % NL;
    int K = PREK[li];         // multiple of 16
    int W = (K + 63) >> 6;
    int lane = threadIdx.x;
    bool act = lane < W;
    const unsigned long long* m = mask + (size_t)bl * MASKROWS * MASKW + lane;
    unsigned long long removed = 0;
    constexpr int D = 16;
    unsigned long long buf[D];
#pragma unroll
    for (int d = 0; d < D; ++d) buf[d] = act ? m[(size_t)d * MASKW] : 0ull;
    unsigned long long local = 0;
    for (int i = 0; i < K; i += D) {
#pragma unroll
        for (int d = 0; d < D; ++d) {
            int ii = i + d;
            unsigned long long row = buf[d];
            int nr = ii + D;
            buf[d] = (act && nr < K) ? m[(size_t)nr * MASKW] : 0ull;  // prefetch D ahead
            int g = ii >> 6;
            if ((ii & 63) == 0) local = shfl_u64(removed, g);  // group start: resync broadcast copy
            unsigned long long rg = shfl_u64(row, g);          // row's word g (off critical path)
            bool keptb = ((local >> (ii & 63)) & 1ull) == 0ull;  // wave-uniform
            unsigned long long sel = keptb ? ~0ull : 0ull;
            if (lane >= g) removed |= row & sel;  // low words of row are unwritten garbage
            local |= rg & sel;
        }
    }
    if (act) {
        int remn = K - lane * 64;
        unsigned long long valid = (remn >= 64) ? ~0ull : ((1ull << remn) - 1ull);
        kept[bl * MASKW + lane] = (~removed) & valid;
    }
}

// ---------------- 7) per-level output: compact kept, zero-pad, concat ----------------
__global__ void k_lvlout(const unsigned long long* __restrict__ kept,
                         const float* __restrict__ sels, const float4* __restrict__ selb,
                         float* __restrict__ cscores, float4* __restrict__ cboxes) {
    int bl = blockIdx.x;
    int b = bl / NL, li = bl % NL;
    int K = PREK[li];
    int W = (K + 63) >> 6;
    int PK = POSTK[li];
    int tid = threadIdx.x;  // 256
    __shared__ unsigned long long kw[32];
    __shared__ int pref[33];
    if (tid < W) kw[tid] = kept[bl * MASKW + tid];
    __syncthreads();
    if (tid == 0) {
        int run = 0;
        for (int w = 0; w < W; ++w) { pref[w] = run; run += __popcll(kw[w]); }
        pref[W] = run;
    }
    __syncthreads();
    int total = pref[W];
    int nused = min(total, PK);
    float* cs = cscores + (size_t)b * CONCATN + COFF[li];
    float4* cbx = cboxes + (size_t)b * CONCATN + COFF[li];
    if (tid < W) {
        int rank = pref[tid];
        unsigned long long w64 = kw[tid];
        while (w64 != 0ull && rank < PK) {
            int j = __ffsll(w64) - 1;
            w64 &= (w64 - 1);
            int pidx = tid * 64 + j;
            cs[rank] = sels[(size_t)bl * SELSTRIDE + pidx];
            cbx[rank] = selb[(size_t)bl * SELSTRIDE + pidx];
            ++rank;
        }
    }
    for (int r = nused + tid; r < PK; r += 256) {
        cs[r] = 0.f;
        cbx[r] = make_float4(0.f, 0.f, 0.f, 0.f);
    }
}

// ---------------- 8) final per-batch top-1000 ----------------
__global__ __launch_bounds__(1024) void k_final(const float* __restrict__ cscores,
                                                const float4* __restrict__ cboxes,
                                                float* __restrict__ out) {
    __shared__ unsigned long long keys[8192];  // 64 KiB
    int b = blockIdx.x;
    int tid = threadIdx.x;
    const float* cs = cscores + (size_t)b * CONCATN;
    for (int i = tid; i < 8192; i += 1024)
        keys[i] = (i < CONCATN)
                      ? (((unsigned long long)__float_as_uint(cs[i]) << 32) |
                         (unsigned long long)(0xFFFFFFFFu - (unsigned int)i))
                      : 0ull;
    bitonic_desc(keys, 8192, tid, 1024);
    const float4* cbx = cboxes + (size_t)b * CONCATN;
    float4* ob = reinterpret_cast<float4*>(out) + (size_t)b * 1000;
    float* os = out + (size_t)BATCH * 1000 * 4 + (size_t)b * 1000;
    for (int r = tid; r < 1000; r += 1024) {
        unsigned long long kk = keys[r];
        unsigned int q = 0xFFFFFFFFu - (unsigned int)(kk & 0xFFFFFFFFull);
        ob[r] = cbx[q];
        os[r] = __uint_as_float((unsigned int)(kk >> 32));
    }
}

// ---------------- launcher ----------------
extern "C" void kernel_launch(void* const* d_in, const int* in_sizes, int n_in,
                              void* d_out, int out_size, void* d_ws, size_t ws_size,
                              hipStream_t stream) {
    Ptrs p;
    // setup_inputs() dict order: (boxes,scores,anchors) per level, then image_shape.
    bool dict_order = (in_sizes[2] == 6291456);
    for (int l = 0; l < 5; ++l) {
        if (dict_order) {
            p.bx[l] = (const float*)d_in[3 * l + 0];
            p.sc[l] = (const float*)d_in[3 * l + 1];
            p.an[l] = (const float*)d_in[3 * l + 2];
        } else {
            p.bx[l] = (const float*)d_in[l];
            p.sc[l] = (const float*)d_in[5 + l];
            p.an[l] = (const float*)d_in[10 + l];
        }
    }
    p.img = (const float*)d_in[15];

    char* ws = (char*)d_ws;
    size_t off = 0;
    auto walloc = [&](size_t sz) -> void* {
        void* r = ws + off;
        off = (off + sz + 255) & ~(size_t)255;
        return r;
    };
    unsigned int* hist         = (unsigned int*)walloc((size_t)40 * NBINS * 4);
    unsigned int* cntR         = (unsigned int*)walloc((size_t)NREP * 64 * 4);
    int* T                     = (int*)walloc(40 * 4);
    unsigned long long* cand   = (unsigned long long*)walloc((size_t)40 * NREP * REPCAP * 8);
    float4* selb               = (float4*)walloc((size_t)40 * SELSTRIDE * 16);
    float* sels                = (float*)walloc((size_t)40 * SELSTRIDE * 4);
    unsigned long long* mask   = (unsigned long long*)walloc((size_t)40 * MASKROWS * MASKW * 8);
    unsigned long long* kept   = (unsigned long long*)walloc((size_t)40 * MASKW * 8);
    float* cscores             = (float*)walloc((size_t)BATCH * CONCATN * 4);
    float4* cboxes             = (float4*)walloc((size_t)BATCH * CONCATN * 16);
    (void)ws_size;

    hipMemsetAsync(hist, 0, (size_t)40 * NBINS * 4, stream);
    hipMemsetAsync(cntR, 0, (size_t)NREP * 64 * 4, stream);

    k_hist<<<BATCH * 11, 1024, 0, stream>>>(p, hist);
    k_findbin<<<40, 256, 0, stream>>>(hist, T);
    k_compact<<<(TOTC + 255) / 256, 256, 0, stream>>>(p, T, cand, cntR);
    k_sortsel<<<40, 1024, 0, stream>>>(cand, cntR, p, selb, sels);
    k_mask<<<BATCH * ROWS_PER_BATCH, 256, 0, stream>>>(selb, mask);
    k_scan<<<40, 64, 0, stream>>>(mask, kept);
    k_lvlout<<<40, 256, 0, stream>>>(kept, sels, selb, cscores, cboxes);
    k_final<<<8, 1024, 0, stream>>>(cscores, cboxes, (float*)d_out);
}

// Round 6
// 553.930 us; speedup vs baseline: 3.0264x; 1.0387x over previous
//
#include <hip/hip_runtime.h>
#include <hip/hip_bf16.h>
#include <cstdint>

// ---------------- problem constants ----------------
constexpr int BATCH = 8;
constexpr int NL = 5;
constexpr int CNTS[5] = {196608, 49152, 12288, 3072, 768};
constexpr int LOFF[5] = {0, 196608, 245760, 258048, 261120};
constexpr int PERB  = 261888;               // candidates per batch
constexpr int TOTC  = BATCH * PERB;         // 2,095,104
constexpr int PREK[5]  = {2000, 2000, 2000, 2000, 768};
constexpr int POSTK[5] = {1000, 1000, 1000, 1000, 768};
constexpr int COFF[5]  = {0, 1000, 2000, 3000, 4000};
constexpr int CONCATN  = 4768;
constexpr int SELSTRIDE = 2048;             // padded per-(b,l) selection stride
constexpr int CANDCAP   = 8192;             // total candidate capacity per (b,l)
constexpr int NREP      = 64;               // counter/region replicas per (b,l)
constexpr int REPCAP    = 512;              // slots per replica region
constexpr int NBINS     = 16384;            // score bins = float bits >> 16 (sig<=1.0 -> max 16256)
constexpr int MASKROWS  = 2000;
constexpr int MASKW     = 32;               // u64 words per mask row
constexpr int SCH       = 128;              // k_scan rows per LDS chunk
constexpr int ROWS_PER_BATCH = 4 * 2000 + 768;  // 8768
constexpr float IOU_THR = 0.7f;
constexpr float CLIPV = 4.135166556742356f; // log(1000/16)

struct Ptrs {
    const float* bx[5];
    const float* sc[5];
    const float* an[5];
    const float* img;
};

// ---------------- helpers ----------------
__device__ __forceinline__ void bitonic_desc(unsigned long long* k, int N, int tid, int nt) {
    for (int kk = 2; kk <= N; kk <<= 1) {
        for (int j = kk >> 1; j > 0; j >>= 1) {
            __syncthreads();
            for (int i = tid; i < N; i += nt) {
                int ixj = i ^ j;
                if (ixj > i) {
                    bool up = ((i & kk) == 0);
                    unsigned long long a = k[i], b = k[ixj];
                    if ((a < b) == up) { k[i] = b; k[ixj] = a; }
                }
            }
        }
    }
    __syncthreads();
}

__device__ __forceinline__ unsigned long long shfl_u64(unsigned long long v, int src) {
    unsigned int lo = (unsigned int)v;
    unsigned int hi = (unsigned int)(v >> 32);
    lo = __shfl(lo, src);
    hi = __shfl(hi, src);
    return ((unsigned long long)hi << 32) | lo;
}

// ---------------- 1) score histogram (LDS-privatized) ----------------
// One block per 32K-element chunk of a (b,l) segment: 11 chunks/batch, 88 blocks.
// 16384 bins of (sigmoid bits >> 16), packed 2x16-bit per LDS word (32 KiB).
__global__ __launch_bounds__(1024) void k_hist(Ptrs p, unsigned int* __restrict__ hist) {
#pragma clang fp contract(off)
    __shared__ unsigned int h2[NBINS / 2];
    constexpr int CLI[11] = {0, 0, 0, 0, 0, 0, 1, 1, 2, 3, 4};
    constexpr int COF[11] = {0, 32768, 65536, 98304, 131072, 163840, 0, 24576, 0, 0, 0};
    constexpr int CLN[11] = {32768, 32768, 32768, 32768, 32768, 32768, 24576, 24576, 12288, 3072, 768};
    int blk = blockIdx.x;
    int b = blk / 11, c = blk % 11;
    int li = CLI[c], off = COF[c], len = CLN[c];
    int tid = threadIdx.x;
    for (int i = tid; i < NBINS / 2; i += 1024) h2[i] = 0;
    __syncthreads();
    const float* sp = p.sc[li] + (size_t)b * CNTS[li] + off;
    for (int i = tid; i < len; i += 1024) {
        float s = sp[i];
        float sig = 1.0f / (1.0f + expf(-s));
        unsigned int bin = __float_as_uint(sig) >> 16;
        atomicAdd(&h2[bin >> 1], 1u << ((bin & 1) << 4));
    }
    __syncthreads();
    unsigned int* H = hist + (size_t)(b * NL + li) * NBINS;
    for (int i = tid; i < NBINS / 2; i += 1024) {
        unsigned int v = h2[i];
        if (v & 0xFFFFu) atomicAdd(&H[2 * i], v & 0xFFFFu);
        if (v >> 16) atomicAdd(&H[2 * i + 1], v >> 16);
    }
}

// ---------------- 2) find threshold bin per (b,l) ----------------
__global__ void k_findbin(const unsigned int* __restrict__ hist, int* __restrict__ T) {
    int bl = blockIdx.x;
    int li = bl % NL;
    unsigned int K = (unsigned int)PREK[li];
    __shared__ unsigned int csum[256];
    const unsigned int* h = hist + (size_t)bl * NBINS;
    int tid = threadIdx.x;  // 256 threads, 64 bins each
    unsigned int s = 0;
    for (int k = 0; k < 64; ++k) s += h[tid * 64 + k];
    csum[tid] = s;
    __syncthreads();
    if (tid == 0) {
        unsigned int cum = 0;
        int t = 0;
        for (int c = 255; c >= 0; --c) {
            if (cum + csum[c] >= K) {
                for (int bin = c * 64 + 63; bin >= c * 64; --bin) {
                    cum += h[bin];
                    if (cum >= K) { t = bin; break; }
                }
                break;
            }
            cum += csum[c];
        }
        T[bl] = t;
    }
}

// ---------------- 3) compact candidates >= threshold bin ----------------
// Wave-aggregated atomic + 64x replicated counters (each replica set in its own
// 256B region -> contention spread over 64 cache lines). Each replica owns a
// fixed 512-slot region of cand.
__global__ void k_compact(Ptrs p, const int* __restrict__ T,
                          unsigned long long* __restrict__ cand, unsigned int* __restrict__ cntR) {
#pragma clang fp contract(off)
    int g = blockIdx.x * blockDim.x + threadIdx.x;
    if (g >= TOTC) return;
    int b = g / PERB;
    int r = g - b * PERB;
    int li;
    if      (r < LOFF[1]) li = 0;
    else if (r < LOFF[2]) li = 1;
    else if (r < LOFF[3]) li = 2;
    else if (r < LOFF[4]) li = 3;
    else                  li = 4;
    int i = r - LOFF[li];
    int bl = b * NL + li;
    int rep = blockIdx.x & (NREP - 1);

    float s = p.sc[li][(size_t)b * CNTS[li] + i];
    float sig = 1.0f / (1.0f + expf(-s));
    unsigned int bits = __float_as_uint(sig);
    bool pass = ((int)(bits >> 16) >= T[bl]);
    unsigned long long ball = __ballot(pass);
    int lane = threadIdx.x & 63;
    unsigned int base = 0;
    if (lane == 0 && ball != 0ull)
        base = atomicAdd(&cntR[rep * 64 + bl], (unsigned int)__popcll(ball));
    base = __shfl((int)base, 0);
    if (pass) {
        unsigned int pos = base + (unsigned int)__popcll(ball & ((1ull << lane) - 1ull));
        if (pos < REPCAP)
            cand[((size_t)bl * NREP + rep) * REPCAP + pos] =
                ((unsigned long long)bits << 32) | (unsigned long long)(0xFFFFFFFFu - (unsigned int)i);
    }
}

// ---------------- 4) sort selected, decode+clip only the top-K boxes ----------------
__global__ __launch_bounds__(1024) void k_sortsel(const unsigned long long* __restrict__ cand,
                                                  const unsigned int* __restrict__ cntR, Ptrs p,
                                                  float4* __restrict__ selb, float* __restrict__ sels) {
#pragma clang fp contract(off)
    __shared__ unsigned long long keys[CANDCAP];  // 64 KiB
    __shared__ int pref[NREP + 1];
    int bl = blockIdx.x;
    int tid = threadIdx.x;
    int b = bl / NL, li = bl % NL;
    int K = PREK[li];
    if (tid == 0) {
        int run = 0;
        for (int rp = 0; rp < NREP; ++rp) {
            pref[rp] = run;
            int c = min((int)cntR[rp * 64 + bl], REPCAP);
            if (run + c > CANDCAP) c = CANDCAP - run;
            run += c;
        }
        pref[NREP] = run;
    }
    __syncthreads();
    int n = pref[NREP];
    int N = 1024;
    while (N < n) N <<= 1;
    for (int i = tid; i < N; i += 1024) keys[i] = 0ull;
    __syncthreads();
    for (int rp = 0; rp < NREP; ++rp) {
        int base = pref[rp], c = pref[rp + 1] - pref[rp];
        const unsigned long long* src = cand + ((size_t)bl * NREP + rp) * REPCAP;
        for (int j = tid; j < c; j += 1024) keys[base + j] = src[j];
    }
    bitonic_desc(keys, N, tid, 1024);

    int nn = CNTS[li];
    float hmax = p.img[b * 2 + 0];
    float wmax = p.img[b * 2 + 1];
    const float4* bxp = reinterpret_cast<const float4*>(p.bx[li]) + (size_t)b * nn;
    const float4* anp = reinterpret_cast<const float4*>(p.an[li]) + (size_t)b * nn;
    for (int r = tid; r < K; r += 1024) {
        unsigned long long kk = keys[r];
        unsigned int idx = 0xFFFFFFFFu - (unsigned int)(kk & 0xFFFFFFFFull);
        const float4 e = bxp[idx];
        const float4 a = anp[idx];
        float dy = e.x, dx = e.y;
        float dh = fminf(e.z, CLIPV), dw = fminf(e.w, CLIPV);
        float ah = a.z - a.x, aw = a.w - a.y;
        float ayc = a.x + 0.5f * ah, axc = a.y + 0.5f * aw;
        float yc = dy * ah + ayc, xc = dx * aw + axc;
        float h = expf(dh) * ah, w = expf(dw) * aw;
        float y0 = yc - 0.5f * h, x0 = xc - 0.5f * w;
        float y1 = yc + 0.5f * h, x1 = xc + 0.5f * w;
        y0 = fminf(fmaxf(y0, 0.f), hmax);
        x0 = fminf(fmaxf(x0, 0.f), wmax);
        y1 = fminf(fmaxf(y1, 0.f), hmax);
        x1 = fminf(fmaxf(x1, 0.f), wmax);
        sels[(size_t)bl * SELSTRIDE + r] = __uint_as_float((unsigned int)(kk >> 32));
        selb[(size_t)bl * SELSTRIDE + r] = make_float4(y0, x0, y1, x1);
    }
}

// ---------------- 5) build triangular suppression bitmask ----------------
__global__ void k_mask(const float4* __restrict__ selb, unsigned long long* __restrict__ mask) {
#pragma clang fp contract(off)
    int rg = blockIdx.x;
    int b = rg / ROWS_PER_BATCH;
    int rem = rg - b * ROWS_PER_BATCH;
    int li, i;
    if (rem < 8000) { li = rem / 2000; i = rem - li * 2000; }
    else            { li = 4; i = rem - 8000; }
    int bl = b * NL + li;
    int K = PREK[li];
    const float4* bb = selb + (size_t)bl * SELSTRIDE;
    float4 bi = bb[i];
    float ai = (bi.z - bi.x) * (bi.w - bi.y);
    int tid = threadIdx.x;  // 256
    unsigned long long* mrow = mask + ((size_t)bl * MASKROWS + i) * MASKW;
    for (int cb = (i >> 6) << 6; cb < K; cb += 256) {
        int c = cb + tid;
        bool sup = false;
        if (c > i && c < K) {
            float4 bj = bb[c];
            float aj = (bj.z - bj.x) * (bj.w - bj.y);
            float iy = fmaxf(0.f, fminf(bi.z, bj.z) - fmaxf(bi.x, bj.x));
            float ix = fmaxf(0.f, fminf(bi.w, bj.w) - fmaxf(bi.y, bj.y));
            float inter = iy * ix;
            float iou = inter / (ai + aj - inter + 1e-8f);
            sup = iou > IOU_THR;
        }
        unsigned long long bal = __ballot(sup);
        int wb = cb + (tid & ~63);  // wave's base column
        if ((tid & 63) == 0 && wb < K) mrow[wb >> 6] = bal;
    }
}

// ---------------- 6) greedy NMS scan (chunked-LDS, early-exit) ----------------
// One 256-thread block per (b,l). Waves 1-3 stream the next 128-row chunk
// (32 KiB) into LDS with coalesced 16B loads while wave 0 scans the current
// chunk from LDS (serial `local`-broadcast chain, ~4 VALU/row). Exact early
// exit: row i's kept status depends only on earlier rows, and only the first
// POSTK kept rows reach the output (scores sorted; suppressed score == 0.0),
// so once keptcnt >= POSTK at a chunk boundary we stop and mark the remaining
// words suppressed.
__global__ __launch_bounds__(256) void k_scan(const unsigned long long* __restrict__ mask,
                                              unsigned long long* __restrict__ kept) {
    __shared__ unsigned long long lbuf[2][SCH * MASKW];  // 2 x 32 KiB
    __shared__ int stopflag;
    int bl = blockIdx.x;
    int li = bl % NL;
    int K = PREK[li];
    int W = (K + 63) >> 6;
    int PK = POSTK[li];
    int tid = threadIdx.x;
    int lane = tid & 63;
    int wv = tid >> 6;
    const unsigned long long* m = mask + (size_t)bl * MASKROWS * MASKW;
    int nchunks = (K + SCH - 1) / SCH;

    auto load_chunk = [&](int c, int t0, int nt) {
        int rbase = c * SCH;
        int nrows = min(SCH, K - rbase);
        int nu2 = nrows * (MASKW / 2);  // ulonglong2 elements (always multiple of nt)
        const ulonglong2* src = reinterpret_cast<const ulonglong2*>(m + (size_t)rbase * MASKW);
        ulonglong2* dst = reinterpret_cast<ulonglong2*>(lbuf[c & 1]);
        if (tid >= t0)
            for (int j = tid - t0; j < nu2; j += nt) dst[j] = src[j];
    };

    if (tid == 0) stopflag = 0;
    load_chunk(0, 0, 256);
    __syncthreads();

    unsigned long long removed = 0, local = 0;
    int keptcnt = 0;
    for (int c = 0; c < nchunks; ++c) {
        if (c + 1 < nchunks) load_chunk(c + 1, 64, 192);  // waves 1-3 prefetch
        if (wv == 0) {
            const unsigned long long* ch = lbuf[c & 1];
            int rbase = c * SCH;
            int nrows = min(SCH, K - rbase);
#pragma unroll 8
            for (int d = 0; d < nrows; ++d) {
                unsigned long long row = (lane < MASKW) ? ch[d * MASKW + lane] : 0ull;
                int ii = rbase + d;
                int g = ii >> 6;
                if ((ii & 63) == 0) local = shfl_u64(removed, g);  // resync broadcast copy
                unsigned long long rg = shfl_u64(row, g);          // off the serial chain
                bool keptb = ((local >> (ii & 63)) & 1ull) == 0ull;  // wave-uniform
                unsigned long long sel = keptb ? ~0ull : 0ull;
                if (lane >= g) removed |= row & sel;  // low words of row are unwritten garbage
                local |= rg & sel;
                keptcnt += keptb ? 1 : 0;
            }
            if (keptcnt >= PK && c + 1 < nchunks) {
                // rows beyond this chunk can't reach the output: mark suppressed
                if (lane >= (c + 1) * (SCH / 64)) removed = ~0ull;
                if (lane == 0) stopflag = 1;
            }
        }
        __syncthreads();
        if (stopflag) break;
    }
    if (wv == 0 && lane < W) {
        int remn = K - lane * 64;
        unsigned long long valid = (remn >= 64) ? ~0ull : ((1ull << remn) - 1ull);
        kept[bl * MASKW + lane] = (~removed) & valid;
    }
}

// ---------------- 7) per-level output: compact kept, zero-pad, concat ----------------
__global__ void k_lvlout(const unsigned long long* __restrict__ kept,
                         const float* __restrict__ sels, const float4* __restrict__ selb,
                         float* __restrict__ cscores, float4* __restrict__ cboxes) {
    int bl = blockIdx.x;
    int b = bl / NL, li = bl % NL;
    int K = PREK[li];
    int W = (K + 63) >> 6;
    int PK = POSTK[li];
    int tid = threadIdx.x;  // 256
    __shared__ unsigned long long kw[32];
    __shared__ int pref[33];
    if (tid < W) kw[tid] = kept[bl * MASKW + tid];
    __syncthreads();
    if (tid == 0) {
        int run = 0;
        for (int w = 0; w < W; ++w) { pref[w] = run; run += __popcll(kw[w]); }
        pref[W] = run;
    }
    __syncthreads();
    int total = pref[W];
    int nused = min(total, PK);
    float* cs = cscores + (size_t)b * CONCATN + COFF[li];
    float4* cbx = cboxes + (size_t)b * CONCATN + COFF[li];
    if (tid < W) {
        int rank = pref[tid];
        unsigned long long w64 = kw[tid];
        while (w64 != 0ull && rank < PK) {
            int j = __ffsll(w64) - 1;
            w64 &= (w64 - 1);
            int pidx = tid * 64 + j;
            cs[rank] = sels[(size_t)bl * SELSTRIDE + pidx];
            cbx[rank] = selb[(size_t)bl * SELSTRIDE + pidx];
            ++rank;
        }
    }
    for (int r = nused + tid; r < PK; r += 256) {
        cs[r] = 0.f;
        cbx[r] = make_float4(0.f, 0.f, 0.f, 0.f);
    }
}

// ---------------- 8) final per-batch top-1000 ----------------
__global__ __launch_bounds__(1024) void k_final(const float* __restrict__ cscores,
                                                const float4* __restrict__ cboxes,
                                                float* __restrict__ out) {
    __shared__ unsigned long long keys[8192];  // 64 KiB
    int b = blockIdx.x;
    int tid = threadIdx.x;
    const float* cs = cscores + (size_t)b * CONCATN;
    for (int i = tid; i < 8192; i += 1024)
        keys[i] = (i < CONCATN)
                      ? (((unsigned long long)__float_as_uint(cs[i]) << 32) |
                         (unsigned long long)(0xFFFFFFFFu - (unsigned int)i))
                      : 0ull;
    bitonic_desc(keys, 8192, tid, 1024);
    const float4* cbx = cboxes + (size_t)b * CONCATN;
    float4* ob = reinterpret_cast<float4*>(out) + (size_t)b * 1000;
    float* os = out + (size_t)BATCH * 1000 * 4 + (size_t)b * 1000;
    for (int r = tid; r < 1000; r += 1024) {
        unsigned long long kk = keys[r];
        unsigned int q = 0xFFFFFFFFu - (unsigned int)(kk & 0xFFFFFFFFull);
        ob[r] = cbx[q];
        os[r] = __uint_as_float((unsigned int)(kk >> 32));
    }
}

// ---------------- launcher ----------------
extern "C" void kernel_launch(void* const* d_in, const int* in_sizes, int n_in,
                              void* d_out, int out_size, void* d_ws, size_t ws_size,
                              hipStream_t stream) {
    Ptrs p;
    // setup_inputs() dict order: (boxes,scores,anchors) per level, then image_shape.
    bool dict_order = (in_sizes[2] == 6291456);
    for (int l = 0; l < 5; ++l) {
        if (dict_order) {
            p.bx[l] = (const float*)d_in[3 * l + 0];
            p.sc[l] = (const float*)d_in[3 * l + 1];
            p.an[l] = (const float*)d_in[3 * l + 2];
        } else {
            p.bx[l] = (const float*)d_in[l];
            p.sc[l] = (const float*)d_in[5 + l];
            p.an[l] = (const float*)d_in[10 + l];
        }
    }
    p.img = (const float*)d_in[15];

    char* ws = (char*)d_ws;
    size_t off = 0;
    auto walloc = [&](size_t sz) -> void* {
        void* r = ws + off;
        off = (off + sz + 255) & ~(size_t)255;
        return r;
    };
    unsigned int* hist         = (unsigned int*)walloc((size_t)40 * NBINS * 4);
    unsigned int* cntR         = (unsigned int*)walloc((size_t)NREP * 64 * 4);
    int* T                     = (int*)walloc(40 * 4);
    unsigned long long* cand   = (unsigned long long*)walloc((size_t)40 * NREP * REPCAP * 8);
    float4* selb               = (float4*)walloc((size_t)40 * SELSTRIDE * 16);
    float* sels                = (float*)walloc((size_t)40 * SELSTRIDE * 4);
    unsigned long long* mask   = (unsigned long long*)walloc((size_t)40 * MASKROWS * MASKW * 8);
    unsigned long long* kept   = (unsigned long long*)walloc((size_t)40 * MASKW * 8);
    float* cscores             = (float*)walloc((size_t)BATCH * CONCATN * 4);
    float4* cboxes             = (float4*)walloc((size_t)BATCH * CONCATN * 16);
    (void)ws_size;

    hipMemsetAsync(hist, 0, (size_t)40 * NBINS * 4, stream);
    hipMemsetAsync(cntR, 0, (size_t)NREP * 64 * 4, stream);

    k_hist<<<BATCH * 11, 1024, 0, stream>>>(p, hist);
    k_findbin<<<40, 256, 0, stream>>>(hist, T);
    k_compact<<<(TOTC + 255) / 256, 256, 0, stream>>>(p, T, cand, cntR);
    k_sortsel<<<40, 1024, 0, stream>>>(cand, cntR, p, selb, sels);
    k_mask<<<BATCH * ROWS_PER_BATCH, 256, 0, stream>>>(selb, mask);
    k_scan<<<40, 256, 0, stream>>>(mask, kept);
    k_lvlout<<<40, 256, 0, stream>>>(kept, sels, selb, cscores, cboxes);
    k_final<<<8, 1024, 0, stream>>>(cscores, cboxes, (float*)d_out);
}

// Round 7
// 553.862 us; speedup vs baseline: 3.0268x; 1.0001x over previous
//
#include <hip/hip_runtime.h>
#include <hip/hip_bf16.h>
#include <cstdint>

// ---------------- problem constants ----------------
constexpr int BATCH = 8;
constexpr int NL = 5;
constexpr int CNTS[5] = {196608, 49152, 12288, 3072, 768};
constexpr int LOFF[5] = {0, 196608, 245760, 258048, 261120};
constexpr int PERB  = 261888;               // candidates per batch
constexpr int TOTC  = BATCH * PERB;         // 2,095,104
constexpr int PREK[5]  = {2000, 2000, 2000, 2000, 768};
constexpr int POSTK[5] = {1000, 1000, 1000, 1000, 768};
constexpr int COFF[5]  = {0, 1000, 2000, 3000, 4000};
constexpr int CONCATN  = 4768;
constexpr int SELSTRIDE = 2048;             // padded per-(b,l) selection stride
constexpr int CANDCAP   = 8192;             // total candidate capacity per (b,l)
constexpr int NREP      = 64;               // counter/region replicas per (b,l)
constexpr int REPCAP    = 512;              // slots per replica region
constexpr int NBINS     = 16384;            // score bins = float bits >> 16 (sig<=1.0 -> max 16256)
constexpr int MASKROWS  = 2000;
constexpr int MASKW     = 32;               // u64 words per mask row
constexpr int SCH       = 128;              // k_scan rows per LDS chunk
constexpr int ROWS_PER_BATCH = 4 * 2000 + 768;  // 8768
constexpr float IOU_THR = 0.7f;
constexpr float CLIPV = 4.135166556742356f; // log(1000/16)

struct Ptrs {
    const float* bx[5];
    const float* sc[5];
    const float* an[5];
    const float* img;
};

// ---------------- helpers ----------------
__device__ __forceinline__ void bitonic_desc(unsigned long long* k, int N, int tid, int nt) {
    for (int kk = 2; kk <= N; kk <<= 1) {
        for (int j = kk >> 1; j > 0; j >>= 1) {
            __syncthreads();
            for (int i = tid; i < N; i += nt) {
                int ixj = i ^ j;
                if (ixj > i) {
                    bool up = ((i & kk) == 0);
                    unsigned long long a = k[i], b = k[ixj];
                    if ((a < b) == up) { k[i] = b; k[ixj] = a; }
                }
            }
        }
    }
    __syncthreads();
}

// Wave-uniform 64-bit broadcast from lane `src` (src must be wave-uniform).
// v_readlane -> SGPR: no LDS pipe involvement (unlike __shfl's ds_bpermute).
__device__ __forceinline__ unsigned long long readlane_u64(unsigned long long v, int src) {
    unsigned int lo = (unsigned int)v;
    unsigned int hi = (unsigned int)(v >> 32);
    lo = (unsigned int)__builtin_amdgcn_readlane((int)lo, src);
    hi = (unsigned int)__builtin_amdgcn_readlane((int)hi, src);
    return ((unsigned long long)hi << 32) | lo;
}

// ---------------- 1) score histogram (LDS-privatized) ----------------
// One block per 32K-element chunk of a (b,l) segment: 11 chunks/batch, 88 blocks.
// 16384 bins of (sigmoid bits >> 16), packed 2x16-bit per LDS word (32 KiB).
__global__ __launch_bounds__(1024) void k_hist(Ptrs p, unsigned int* __restrict__ hist) {
#pragma clang fp contract(off)
    __shared__ unsigned int h2[NBINS / 2];
    constexpr int CLI[11] = {0, 0, 0, 0, 0, 0, 1, 1, 2, 3, 4};
    constexpr int COF[11] = {0, 32768, 65536, 98304, 131072, 163840, 0, 24576, 0, 0, 0};
    constexpr int CLN[11] = {32768, 32768, 32768, 32768, 32768, 32768, 24576, 24576, 12288, 3072, 768};
    int blk = blockIdx.x;
    int b = blk / 11, c = blk % 11;
    int li = CLI[c], off = COF[c], len = CLN[c];
    int tid = threadIdx.x;
    for (int i = tid; i < NBINS / 2; i += 1024) h2[i] = 0;
    __syncthreads();
    const float* sp = p.sc[li] + (size_t)b * CNTS[li] + off;
    for (int i = tid; i < len; i += 1024) {
        float s = sp[i];
        float sig = 1.0f / (1.0f + expf(-s));
        unsigned int bin = __float_as_uint(sig) >> 16;
        atomicAdd(&h2[bin >> 1], 1u << ((bin & 1) << 4));
    }
    __syncthreads();
    unsigned int* H = hist + (size_t)(b * NL + li) * NBINS;
    for (int i = tid; i < NBINS / 2; i += 1024) {
        unsigned int v = h2[i];
        if (v & 0xFFFFu) atomicAdd(&H[2 * i], v & 0xFFFFu);
        if (v >> 16) atomicAdd(&H[2 * i + 1], v >> 16);
    }
}

// ---------------- 2) find threshold bin per (b,l) ----------------
__global__ void k_findbin(const unsigned int* __restrict__ hist, int* __restrict__ T) {
    int bl = blockIdx.x;
    int li = bl % NL;
    unsigned int K = (unsigned int)PREK[li];
    __shared__ unsigned int csum[256];
    const unsigned int* h = hist + (size_t)bl * NBINS;
    int tid = threadIdx.x;  // 256 threads, 64 bins each
    unsigned int s = 0;
    for (int k = 0; k < 64; ++k) s += h[tid * 64 + k];
    csum[tid] = s;
    __syncthreads();
    if (tid == 0) {
        unsigned int cum = 0;
        int t = 0;
        for (int c = 255; c >= 0; --c) {
            if (cum + csum[c] >= K) {
                for (int bin = c * 64 + 63; bin >= c * 64; --bin) {
                    cum += h[bin];
                    if (cum >= K) { t = bin; break; }
                }
                break;
            }
            cum += csum[c];
        }
        T[bl] = t;
    }
}

// ---------------- 3) compact candidates >= threshold bin ----------------
// Wave-aggregated atomic + 64x replicated counters (each replica set in its own
// 256B region -> contention spread over 64 cache lines). Each replica owns a
// fixed 512-slot region of cand.
__global__ void k_compact(Ptrs p, const int* __restrict__ T,
                          unsigned long long* __restrict__ cand, unsigned int* __restrict__ cntR) {
#pragma clang fp contract(off)
    int g = blockIdx.x * blockDim.x + threadIdx.x;
    if (g >= TOTC) return;
    int b = g / PERB;
    int r = g - b * PERB;
    int li;
    if      (r < LOFF[1]) li = 0;
    else if (r < LOFF[2]) li = 1;
    else if (r < LOFF[3]) li = 2;
    else if (r < LOFF[4]) li = 3;
    else                  li = 4;
    int i = r - LOFF[li];
    int bl = b * NL + li;
    int rep = blockIdx.x & (NREP - 1);

    float s = p.sc[li][(size_t)b * CNTS[li] + i];
    float sig = 1.0f / (1.0f + expf(-s));
    unsigned int bits = __float_as_uint(sig);
    bool pass = ((int)(bits >> 16) >= T[bl]);
    unsigned long long ball = __ballot(pass);
    int lane = threadIdx.x & 63;
    unsigned int base = 0;
    if (lane == 0 && ball != 0ull)
        base = atomicAdd(&cntR[rep * 64 + bl], (unsigned int)__popcll(ball));
    base = __shfl((int)base, 0);
    if (pass) {
        unsigned int pos = base + (unsigned int)__popcll(ball & ((1ull << lane) - 1ull));
        if (pos < REPCAP)
            cand[((size_t)bl * NREP + rep) * REPCAP + pos] =
                ((unsigned long long)bits << 32) | (unsigned long long)(0xFFFFFFFFu - (unsigned int)i);
    }
}

// ---------------- 4) sort selected, decode+clip only the top-K boxes ----------------
__global__ __launch_bounds__(1024) void k_sortsel(const unsigned long long* __restrict__ cand,
                                                  const unsigned int* __restrict__ cntR, Ptrs p,
                                                  float4* __restrict__ selb, float* __restrict__ sels) {
#pragma clang fp contract(off)
    __shared__ unsigned long long keys[CANDCAP];  // 64 KiB
    __shared__ int pref[NREP + 1];
    int bl = blockIdx.x;
    int tid = threadIdx.x;
    int b = bl / NL, li = bl % NL;
    int K = PREK[li];
    if (tid == 0) {
        int run = 0;
        for (int rp = 0; rp < NREP; ++rp) {
            pref[rp] = run;
            int c = min((int)cntR[rp * 64 + bl], REPCAP);
            if (run + c > CANDCAP) c = CANDCAP - run;
            run += c;
        }
        pref[NREP] = run;
    }
    __syncthreads();
    int n = pref[NREP];
    int N = 1024;
    while (N < n) N <<= 1;
    for (int i = tid; i < N; i += 1024) keys[i] = 0ull;
    __syncthreads();
    for (int rp = 0; rp < NREP; ++rp) {
        int base = pref[rp], c = pref[rp + 1] - pref[rp];
        const unsigned long long* src = cand + ((size_t)bl * NREP + rp) * REPCAP;
        for (int j = tid; j < c; j += 1024) keys[base + j] = src[j];
    }
    bitonic_desc(keys, N, tid, 1024);

    int nn = CNTS[li];
    float hmax = p.img[b * 2 + 0];
    float wmax = p.img[b * 2 + 1];
    const float4* bxp = reinterpret_cast<const float4*>(p.bx[li]) + (size_t)b * nn;
    const float4* anp = reinterpret_cast<const float4*>(p.an[li]) + (size_t)b * nn;
    for (int r = tid; r < K; r += 1024) {
        unsigned long long kk = keys[r];
        unsigned int idx = 0xFFFFFFFFu - (unsigned int)(kk & 0xFFFFFFFFull);
        const float4 e = bxp[idx];
        const float4 a = anp[idx];
        float dy = e.x, dx = e.y;
        float dh = fminf(e.z, CLIPV), dw = fminf(e.w, CLIPV);
        float ah = a.z - a.x, aw = a.w - a.y;
        float ayc = a.x + 0.5f * ah, axc = a.y + 0.5f * aw;
        float yc = dy * ah + ayc, xc = dx * aw + axc;
        float h = expf(dh) * ah, w = expf(dw) * aw;
        float y0 = yc - 0.5f * h, x0 = xc - 0.5f * w;
        float y1 = yc + 0.5f * h, x1 = xc + 0.5f * w;
        y0 = fminf(fmaxf(y0, 0.f), hmax);
        x0 = fminf(fmaxf(x0, 0.f), wmax);
        y1 = fminf(fmaxf(y1, 0.f), hmax);
        x1 = fminf(fmaxf(x1, 0.f), wmax);
        sels[(size_t)bl * SELSTRIDE + r] = __uint_as_float((unsigned int)(kk >> 32));
        selb[(size_t)bl * SELSTRIDE + r] = make_float4(y0, x0, y1, x1);
    }
}

// ---------------- 5) build triangular suppression bitmask ----------------
__global__ void k_mask(const float4* __restrict__ selb, unsigned long long* __restrict__ mask) {
#pragma clang fp contract(off)
    int rg = blockIdx.x;
    int b = rg / ROWS_PER_BATCH;
    int rem = rg - b * ROWS_PER_BATCH;
    int li, i;
    if (rem < 8000) { li = rem / 2000; i = rem - li * 2000; }
    else            { li = 4; i = rem - 8000; }
    int bl = b * NL + li;
    int K = PREK[li];
    const float4* bb = selb + (size_t)bl * SELSTRIDE;
    float4 bi = bb[i];
    float ai = (bi.z - bi.x) * (bi.w - bi.y);
    int tid = threadIdx.x;  // 256
    unsigned long long* mrow = mask + ((size_t)bl * MASKROWS + i) * MASKW;
    for (int cb = (i >> 6) << 6; cb < K; cb += 256) {
        int c = cb + tid;
        bool sup = false;
        if (c > i && c < K) {
            float4 bj = bb[c];
            float aj = (bj.z - bj.x) * (bj.w - bj.y);
            float iy = fmaxf(0.f, fminf(bi.z, bj.z) - fmaxf(bi.x, bj.x));
            float ix = fmaxf(0.f, fminf(bi.w, bj.w) - fmaxf(bi.y, bj.y));
            float inter = iy * ix;
            float iou = inter / (ai + aj - inter + 1e-8f);
            sup = iou > IOU_THR;
        }
        unsigned long long bal = __ballot(sup);
        int wb = cb + (tid & ~63);  // wave's base column
        if ((tid & 63) == 0 && wb < K) mrow[wb >> 6] = bal;
    }
}

// ---------------- 6) greedy NMS scan (chunked-LDS, readlane chain, early-exit) ----------------
// One 256-thread block per (b,l). Waves 1-3 stream the next 128-row chunk
// (32 KiB) into LDS while wave 0 scans the current chunk. The serial chain uses
// v_readlane (VALU->SGPR, wave-uniform src lane g = ii>>6) instead of __shfl
// (ds_bpermute): no LDS-pipe latency on the chain. Row ds_reads are independent
// and pipeline under unroll. `local`/kept test are wave-uniform -> uniform
// branch. Exact early exit: once keptcnt >= POSTK at a chunk boundary, later
// rows can't reach the output (scores sorted, suppressed score == 0.0).
__global__ __launch_bounds__(256) void k_scan(const unsigned long long* __restrict__ mask,
                                              unsigned long long* __restrict__ kept) {
    __shared__ unsigned long long lbuf[2][SCH * MASKW];  // 2 x 32 KiB
    __shared__ int stopflag;
    int bl = blockIdx.x;
    int li = bl % NL;
    int K = PREK[li];
    int W = (K + 63) >> 6;
    int PK = POSTK[li];
    int tid = threadIdx.x;
    int lane = tid & 63;
    int wv = tid >> 6;
    const unsigned long long* m = mask + (size_t)bl * MASKROWS * MASKW;
    int nchunks = (K + SCH - 1) / SCH;

    auto load_chunk = [&](int c, int t0, int nt) {
        int rbase = c * SCH;
        int nrows = min(SCH, K - rbase);
        int nu2 = nrows * (MASKW / 2);  // ulonglong2 elements
        const ulonglong2* src = reinterpret_cast<const ulonglong2*>(m + (size_t)rbase * MASKW);
        ulonglong2* dst = reinterpret_cast<ulonglong2*>(lbuf[c & 1]);
        if (tid >= t0)
            for (int j = tid - t0; j < nu2; j += nt) dst[j] = src[j];
    };

    if (tid == 0) stopflag = 0;
    load_chunk(0, 0, 256);
    __syncthreads();

    unsigned long long removed = 0, local = 0;
    int keptcnt = 0;
    for (int c = 0; c < nchunks; ++c) {
        if (c + 1 < nchunks) load_chunk(c + 1, 64, 192);  // waves 1-3 prefetch
        if (wv == 0) {
            const unsigned long long* ch = lbuf[c & 1];
            int rbase = c * SCH;
            int nrows = min(SCH, K - rbase);
#pragma unroll 8
            for (int d = 0; d < nrows; ++d) {
                unsigned long long row = (lane < MASKW) ? ch[d * MASKW + lane] : 0ull;
                int ii = rbase + d;
                int g = ii >> 6;
                if ((ii & 63) == 0) local = readlane_u64(removed, g);  // resync, VALU->SGPR
                unsigned long long rg = readlane_u64(row, g);          // off the SALU chain
                bool keptb = ((local >> (ii & 63)) & 1ull) == 0ull;    // wave-uniform
                if (keptb) {                                           // uniform branch
                    ++keptcnt;
                    if (lane >= g) removed |= row;  // low words of row are unwritten garbage
                    local |= rg;
                }
            }
            if (keptcnt >= PK && c + 1 < nchunks) {
                // rows beyond this chunk can't reach the output: mark suppressed
                if (lane >= (c + 1) * (SCH / 64)) removed = ~0ull;
                if (lane == 0) stopflag = 1;
            }
        }
        __syncthreads();
        if (stopflag) break;
    }
    if (wv == 0 && lane < W) {
        int remn = K - lane * 64;
        unsigned long long valid = (remn >= 64) ? ~0ull : ((1ull << remn) - 1ull);
        kept[bl * MASKW + lane] = (~removed) & valid;
    }
}

// ---------------- 7) per-level output: compact kept, zero-pad, concat ----------------
__global__ void k_lvlout(const unsigned long long* __restrict__ kept,
                         const float* __restrict__ sels, const float4* __restrict__ selb,
                         float* __restrict__ cscores, float4* __restrict__ cboxes) {
    int bl = blockIdx.x;
    int b = bl / NL, li = bl % NL;
    int K = PREK[li];
    int W = (K + 63) >> 6;
    int PK = POSTK[li];
    int tid = threadIdx.x;  // 256
    __shared__ unsigned long long kw[32];
    __shared__ int pref[33];
    if (tid < W) kw[tid] = kept[bl * MASKW + tid];
    __syncthreads();
    if (tid == 0) {
        int run = 0;
        for (int w = 0; w < W; ++w) { pref[w] = run; run += __popcll(kw[w]); }
        pref[W] = run;
    }
    __syncthreads();
    int total = pref[W];
    int nused = min(total, PK);
    float* cs = cscores + (size_t)b * CONCATN + COFF[li];
    float4* cbx = cboxes + (size_t)b * CONCATN + COFF[li];
    if (tid < W) {
        int rank = pref[tid];
        unsigned long long w64 = kw[tid];
        while (w64 != 0ull && rank < PK) {
            int j = __ffsll(w64) - 1;
            w64 &= (w64 - 1);
            int pidx = tid * 64 + j;
            cs[rank] = sels[(size_t)bl * SELSTRIDE + pidx];
            cbx[rank] = selb[(size_t)bl * SELSTRIDE + pidx];
            ++rank;
        }
    }
    for (int r = nused + tid; r < PK; r += 256) {
        cs[r] = 0.f;
        cbx[r] = make_float4(0.f, 0.f, 0.f, 0.f);
    }
}

// ---------------- 8) final per-batch top-1000 ----------------
__global__ __launch_bounds__(1024) void k_final(const float* __restrict__ cscores,
                                                const float4* __restrict__ cboxes,
                                                float* __restrict__ out) {
    __shared__ unsigned long long keys[8192];  // 64 KiB
    int b = blockIdx.x;
    int tid = threadIdx.x;
    const float* cs = cscores + (size_t)b * CONCATN;
    for (int i = tid; i < 8192; i += 1024)
        keys[i] = (i < CONCATN)
                      ? (((unsigned long long)__float_as_uint(cs[i]) << 32) |
                         (unsigned long long)(0xFFFFFFFFu - (unsigned int)i))
                      : 0ull;
    bitonic_desc(keys, 8192, tid, 1024);
    const float4* cbx = cboxes + (size_t)b * CONCATN;
    float4* ob = reinterpret_cast<float4*>(out) + (size_t)b * 1000;
    float* os = out + (size_t)BATCH * 1000 * 4 + (size_t)b * 1000;
    for (int r = tid; r < 1000; r += 1024) {
        unsigned long long kk = keys[r];
        unsigned int q = 0xFFFFFFFFu - (unsigned int)(kk & 0xFFFFFFFFull);
        ob[r] = cbx[q];
        os[r] = __uint_as_float((unsigned int)(kk >> 32));
    }
}

// ---------------- launcher ----------------
extern "C" void kernel_launch(void* const* d_in, const int* in_sizes, int n_in,
                              void* d_out, int out_size, void* d_ws, size_t ws_size,
                              hipStream_t stream) {
    Ptrs p;
    // setup_inputs() dict order: (boxes,scores,anchors) per level, then image_shape.
    bool dict_order = (in_sizes[2] == 6291456);
    for (int l = 0; l < 5; ++l) {
        if (dict_order) {
            p.bx[l] = (const float*)d_in[3 * l + 0];
            p.sc[l] = (const float*)d_in[3 * l + 1];
            p.an[l] = (const float*)d_in[3 * l + 2];
        } else {
            p.bx[l] = (const float*)d_in[l];
            p.sc[l] = (const float*)d_in[5 + l];
            p.an[l] = (const float*)d_in[10 + l];
        }
    }
    p.img = (const float*)d_in[15];

    char* ws = (char*)d_ws;
    size_t off = 0;
    auto walloc = [&](size_t sz) -> void* {
        void* r = ws + off;
        off = (off + sz + 255) & ~(size_t)255;
        return r;
    };
    unsigned int* hist         = (unsigned int*)walloc((size_t)40 * NBINS * 4);
    unsigned int* cntR         = (unsigned int*)walloc((size_t)NREP * 64 * 4);
    int* T                     = (int*)walloc(40 * 4);
    unsigned long long* cand   = (unsigned long long*)walloc((size_t)40 * NREP * REPCAP * 8);
    float4* selb               = (float4*)walloc((size_t)40 * SELSTRIDE * 16);
    float* sels                = (float*)walloc((size_t)40 * SELSTRIDE * 4);
    unsigned long long* mask   = (unsigned long long*)walloc((size_t)40 * MASKROWS * MASKW * 8);
    unsigned long long* kept   = (unsigned long long*)walloc((size_t)40 * MASKW * 8);
    float* cscores             = (float*)walloc((size_t)BATCH * CONCATN * 4);
    float4* cboxes             = (float4*)walloc((size_t)BATCH * CONCATN * 16);
    (void)ws_size;

    hipMemsetAsync(hist, 0, (size_t)40 * NBINS * 4, stream);
    hipMemsetAsync(cntR, 0, (size_t)NREP * 64 * 4, stream);

    k_hist<<<BATCH * 11, 1024, 0, stream>>>(p, hist);
    k_findbin<<<40, 256, 0, stream>>>(hist, T);
    k_compact<<<(TOTC + 255) / 256, 256, 0, stream>>>(p, T, cand, cntR);
    k_sortsel<<<40, 1024, 0, stream>>>(cand, cntR, p, selb, sels);
    k_mask<<<BATCH * ROWS_PER_BATCH, 256, 0, stream>>>(selb, mask);
    k_scan<<<40, 256, 0, stream>>>(mask, kept);
    k_lvlout<<<40, 256, 0, stream>>>(kept, sels, selb, cscores, cboxes);
    k_final<<<8, 1024, 0, stream>>>(cscores, cboxes, (float*)d_out);
}

// Round 9
// 408.163 us; speedup vs baseline: 4.1072x; 1.3570x over previous
//
#include <hip/hip_runtime.h>
#include <hip/hip_bf16.h>
#include <cstdint>

// ---------------- problem constants ----------------
constexpr int BATCH = 8;
constexpr int NL = 5;
constexpr int CNTS[5] = {196608, 49152, 12288, 3072, 768};
constexpr int LOFF[5] = {0, 196608, 245760, 258048, 261120};
constexpr int PERB  = 261888;               // candidates per batch
constexpr int TOTC  = BATCH * PERB;         // 2,095,104
constexpr int PREK[5]  = {2000, 2000, 2000, 2000, 768};
constexpr int POSTK[5] = {1000, 1000, 1000, 1000, 768};
constexpr int COFF[5]  = {0, 1000, 2000, 3000, 4000};
constexpr int CONCATN  = 4768;
constexpr int SELSTRIDE = 2048;             // padded per-(b,l) selection stride
constexpr int CANDCAP   = 8192;             // total candidate capacity per (b,l)
constexpr int NREP      = 64;               // counter/region replicas per (b,l)
constexpr int REPCAP    = 512;              // slots per replica region
constexpr int NBINS     = 16384;            // score bins = float bits >> 16 (sig<=1.0 -> max 16256)
constexpr int MASKROWS  = 2000;
constexpr int MASKW     = 32;               // u64 words per mask row
constexpr int SCH       = 128;              // k_scan rows per LDS chunk
constexpr int ROWS_PER_BATCH = 4 * 2000 + 768;  // 8768
constexpr float IOU_THR = 0.7f;
constexpr float CLIPV = 4.135166556742356f; // log(1000/16)

struct Ptrs {
    const float* bx[5];
    const float* sc[5];
    const float* an[5];
    const float* img;
};

// ---------------- helpers ----------------
__device__ __forceinline__ void bitonic_desc(unsigned long long* k, int N, int tid, int nt) {
    for (int kk = 2; kk <= N; kk <<= 1) {
        for (int j = kk >> 1; j > 0; j >>= 1) {
            __syncthreads();
            for (int i = tid; i < N; i += nt) {
                int ixj = i ^ j;
                if (ixj > i) {
                    bool up = ((i & kk) == 0);
                    unsigned long long a = k[i], b = k[ixj];
                    if ((a < b) == up) { k[i] = b; k[ixj] = a; }
                }
            }
        }
    }
    __syncthreads();
}

// Wave-uniform 64-bit broadcast from lane `src` (src must be wave-uniform).
__device__ __forceinline__ unsigned long long readlane_u64(unsigned long long v, int src) {
    unsigned int lo = (unsigned int)v;
    unsigned int hi = (unsigned int)(v >> 32);
    lo = (unsigned int)__builtin_amdgcn_readlane((int)lo, src);
    hi = (unsigned int)__builtin_amdgcn_readlane((int)hi, src);
    return ((unsigned long long)hi << 32) | lo;
}

// ---------------- 1) score histogram (LDS-privatized) ----------------
__global__ __launch_bounds__(1024) void k_hist(Ptrs p, unsigned int* __restrict__ hist) {
#pragma clang fp contract(off)
    __shared__ unsigned int h2[NBINS / 2];
    constexpr int CLI[11] = {0, 0, 0, 0, 0, 0, 1, 1, 2, 3, 4};
    constexpr int COF[11] = {0, 32768, 65536, 98304, 131072, 163840, 0, 24576, 0, 0, 0};
    constexpr int CLN[11] = {32768, 32768, 32768, 32768, 32768, 32768, 24576, 24576, 12288, 3072, 768};
    int blk = blockIdx.x;
    int b = blk / 11, c = blk % 11;
    int li = CLI[c], off = COF[c], len = CLN[c];
    int tid = threadIdx.x;
    for (int i = tid; i < NBINS / 2; i += 1024) h2[i] = 0;
    __syncthreads();
    const float* sp = p.sc[li] + (size_t)b * CNTS[li] + off;
    for (int i = tid; i < len; i += 1024) {
        float s = sp[i];
        float sig = 1.0f / (1.0f + expf(-s));
        unsigned int bin = __float_as_uint(sig) >> 16;
        atomicAdd(&h2[bin >> 1], 1u << ((bin & 1) << 4));
    }
    __syncthreads();
    unsigned int* H = hist + (size_t)(b * NL + li) * NBINS;
    for (int i = tid; i < NBINS / 2; i += 1024) {
        unsigned int v = h2[i];
        if (v & 0xFFFFu) atomicAdd(&H[2 * i], v & 0xFFFFu);
        if (v >> 16) atomicAdd(&H[2 * i + 1], v >> 16);
    }
}

// ---------------- 2) find threshold bin per (b,l) ----------------
__global__ void k_findbin(const unsigned int* __restrict__ hist, int* __restrict__ T) {
    int bl = blockIdx.x;
    int li = bl % NL;
    unsigned int K = (unsigned int)PREK[li];
    __shared__ unsigned int csum[256];
    const unsigned int* h = hist + (size_t)bl * NBINS;
    int tid = threadIdx.x;  // 256 threads, 64 bins each
    unsigned int s = 0;
    for (int k = 0; k < 64; ++k) s += h[tid * 64 + k];
    csum[tid] = s;
    __syncthreads();
    if (tid == 0) {
        unsigned int cum = 0;
        int t = 0;
        for (int c = 255; c >= 0; --c) {
            if (cum + csum[c] >= K) {
                for (int bin = c * 64 + 63; bin >= c * 64; --bin) {
                    cum += h[bin];
                    if (cum >= K) { t = bin; break; }
                }
                break;
            }
            cum += csum[c];
        }
        T[bl] = t;
    }
}

// ---------------- 3) compact candidates >= threshold bin ----------------
__global__ void k_compact(Ptrs p, const int* __restrict__ T,
                          unsigned long long* __restrict__ cand, unsigned int* __restrict__ cntR) {
#pragma clang fp contract(off)
    int g = blockIdx.x * blockDim.x + threadIdx.x;
    if (g >= TOTC) return;
    int b = g / PERB;
    int r = g - b * PERB;
    int li;
    if      (r < LOFF[1]) li = 0;
    else if (r < LOFF[2]) li = 1;
    else if (r < LOFF[3]) li = 2;
    else if (r < LOFF[4]) li = 3;
    else                  li = 4;
    int i = r - LOFF[li];
    int bl = b * NL + li;
    int rep = blockIdx.x & (NREP - 1);

    float s = p.sc[li][(size_t)b * CNTS[li] + i];
    float sig = 1.0f / (1.0f + expf(-s));
    unsigned int bits = __float_as_uint(sig);
    bool pass = ((int)(bits >> 16) >= T[bl]);
    unsigned long long ball = __ballot(pass);
    int lane = threadIdx.x & 63;
    unsigned int base = 0;
    if (lane == 0 && ball != 0ull)
        base = atomicAdd(&cntR[rep * 64 + bl], (unsigned int)__popcll(ball));
    base = __shfl((int)base, 0);
    if (pass) {
        unsigned int pos = base + (unsigned int)__popcll(ball & ((1ull << lane) - 1ull));
        if (pos < REPCAP)
            cand[((size_t)bl * NREP + rep) * REPCAP + pos] =
                ((unsigned long long)bits << 32) | (unsigned long long)(0xFFFFFFFFu - (unsigned int)i);
    }
}

// ---------------- 4) sort selected, decode+clip only the top-K boxes ----------------
__global__ __launch_bounds__(1024) void k_sortsel(const unsigned long long* __restrict__ cand,
                                                  const unsigned int* __restrict__ cntR, Ptrs p,
                                                  float4* __restrict__ selb, float* __restrict__ sels) {
#pragma clang fp contract(off)
    __shared__ unsigned long long keys[CANDCAP];  // 64 KiB
    __shared__ int pref[NREP + 1];
    int bl = blockIdx.x;
    int tid = threadIdx.x;
    int b = bl / NL, li = bl % NL;
    int K = PREK[li];
    if (tid == 0) {
        int run = 0;
        for (int rp = 0; rp < NREP; ++rp) {
            pref[rp] = run;
            int c = min((int)cntR[rp * 64 + bl], REPCAP);
            if (run + c > CANDCAP) c = CANDCAP - run;
            run += c;
        }
        pref[NREP] = run;
    }
    __syncthreads();
    int n = pref[NREP];
    int N = 1024;
    while (N < n) N <<= 1;
    for (int i = tid; i < N; i += 1024) keys[i] = 0ull;
    __syncthreads();
    for (int rp = 0; rp < NREP; ++rp) {
        int base = pref[rp], c = pref[rp + 1] - pref[rp];
        const unsigned long long* src = cand + ((size_t)bl * NREP + rp) * REPCAP;
        for (int j = tid; j < c; j += 1024) keys[base + j] = src[j];
    }
    bitonic_desc(keys, N, tid, 1024);

    int nn = CNTS[li];
    float hmax = p.img[b * 2 + 0];
    float wmax = p.img[b * 2 + 1];
    const float4* bxp = reinterpret_cast<const float4*>(p.bx[li]) + (size_t)b * nn;
    const float4* anp = reinterpret_cast<const float4*>(p.an[li]) + (size_t)b * nn;
    for (int r = tid; r < K; r += 1024) {
        unsigned long long kk = keys[r];
        unsigned int idx = 0xFFFFFFFFu - (unsigned int)(kk & 0xFFFFFFFFull);
        const float4 e = bxp[idx];
        const float4 a = anp[idx];
        float dy = e.x, dx = e.y;
        float dh = fminf(e.z, CLIPV), dw = fminf(e.w, CLIPV);
        float ah = a.z - a.x, aw = a.w - a.y;
        float ayc = a.x + 0.5f * ah, axc = a.y + 0.5f * aw;
        float yc = dy * ah + ayc, xc = dx * aw + axc;
        float h = expf(dh) * ah, w = expf(dw) * aw;
        float y0 = yc - 0.5f * h, x0 = xc - 0.5f * w;
        float y1 = yc + 0.5f * h, x1 = xc + 0.5f * w;
        y0 = fminf(fmaxf(y0, 0.f), hmax);
        x0 = fminf(fmaxf(x0, 0.f), wmax);
        y1 = fminf(fmaxf(y1, 0.f), hmax);
        x1 = fminf(fmaxf(x1, 0.f), wmax);
        sels[(size_t)bl * SELSTRIDE + r] = __uint_as_float((unsigned int)(kk >> 32));
        selb[(size_t)bl * SELSTRIDE + r] = make_float4(y0, x0, y1, x1);
    }
}

// ---------------- 5) build triangular suppression bitmask ----------------
__global__ void k_mask(const float4* __restrict__ selb, unsigned long long* __restrict__ mask) {
#pragma clang fp contract(off)
    int rg = blockIdx.x;
    int b = rg / ROWS_PER_BATCH;
    int rem = rg - b * ROWS_PER_BATCH;
    int li, i;
    if (rem < 8000) { li = rem / 2000; i = rem - li * 2000; }
    else            { li = 4; i = rem - 8000; }
    int bl = b * NL + li;
    int K = PREK[li];
    const float4* bb = selb + (size_t)bl * SELSTRIDE;
    float4 bi = bb[i];
    float ai = (bi.z - bi.x) * (bi.w - bi.y);
    int tid = threadIdx.x;  // 256
    unsigned long long* mrow = mask + ((size_t)bl * MASKROWS + i) * MASKW;
    for (int cb = (i >> 6) << 6; cb < K; cb += 256) {
        int c = cb + tid;
        bool sup = false;
        if (c > i && c < K) {
            float4 bj = bb[c];
            float aj = (bj.z - bj.x) * (bj.w - bj.y);
            float iy = fmaxf(0.f, fminf(bi.z, bj.z) - fmaxf(bi.x, bj.x));
            float ix = fmaxf(0.f, fminf(bi.w, bj.w) - fmaxf(bi.y, bj.y));
            float inter = iy * ix;
            float iou = inter / (ai + aj - inter + 1e-8f);
            sup = iou > IOU_THR;
        }
        unsigned long long bal = __ballot(sup);
        int wb = cb + (tid & ~63);  // wave's base column
        if ((tid & 63) == 0 && wb < K) mrow[wb >> 6] = bal;
    }
}

// ---------------- 6) greedy NMS scan (chunked-LDS, branchless register pipeline) ----------------
// One 256-thread block per (b,l). Waves 1-3 stream the next 128-row chunk into
// LDS while wave 0 scans the current chunk. Per-row update is branchless pure
// VALU: `local` (wave-uniform copy of current group's removed-word) is fed by a
// SAME-ADDRESS LDS read ch[row*32+g] (hardware broadcast -> uniform), removing
// all cross-lane ops from the chain. Rows processed in 8-row register windows,
// window w+1's 16 ds_reads issued BEFORE processing window w (A/B reg sets,
// static indexing) so LDS latency is hidden. One readlane per 64-row group.
// Exact early exit at chunk boundaries once keptcnt >= POSTK.
__global__ __launch_bounds__(256) void k_scan(const unsigned long long* __restrict__ mask,
                                              unsigned long long* __restrict__ kept) {
    __shared__ unsigned long long lbuf[2][SCH * MASKW];  // 2 x 32 KiB
    __shared__ int stopflag;
    int bl = blockIdx.x;
    int li = bl % NL;
    int K = PREK[li];
    int W = (K + 63) >> 6;
    int PK = POSTK[li];
    int tid = threadIdx.x;
    int lane = tid & 63;
    int wv = tid >> 6;
    const unsigned long long* m = mask + (size_t)bl * MASKROWS * MASKW;
    int nchunks = (K + SCH - 1) / SCH;

    auto load_chunk = [&](int c, int t0, int nt) {
        int rbase = c * SCH;
        int nrows = min(SCH, K - rbase);
        int nu2 = nrows * (MASKW / 2);  // ulonglong2 elements
        const ulonglong2* src = reinterpret_cast<const ulonglong2*>(m + (size_t)rbase * MASKW);
        ulonglong2* dst = reinterpret_cast<ulonglong2*>(lbuf[c & 1]);
        if (tid >= t0)
            for (int j = tid - t0; j < nu2; j += nt) dst[j] = src[j];
    };

    if (tid == 0) stopflag = 0;
    load_chunk(0, 0, 256);
    __syncthreads();

    unsigned long long removed = 0, local = 0;
    int keptcnt = 0;
    for (int c = 0; c < nchunks; ++c) {
        if (c + 1 < nchunks) load_chunk(c + 1, 64, 192);  // waves 1-3 prefetch
        if (wv == 0) {
            const unsigned long long* ch = lbuf[c & 1];
            int rbase = c * SCH;
            int nrows = min(SCH, K - rbase);  // multiple of 8

            unsigned long long rvA[8], rgA[8], rvB[8], rgB[8];
            auto loadw = [&](unsigned long long (&rv)[8], unsigned long long (&rg)[8], int w0) {
                int g = (rbase + w0) >> 6;
#pragma unroll
                for (int k2 = 0; k2 < 8; ++k2) {
                    rv[k2] = ch[(w0 + k2) * MASKW + (lane & (MASKW - 1))];
                    rg[k2] = ch[(w0 + k2) * MASKW + g];  // same addr all lanes -> broadcast
                }
            };
            auto procw = [&](unsigned long long (&rv)[8], unsigned long long (&rg)[8], int w0) {
                int ii0 = rbase + w0;
                int g = ii0 >> 6;
                if ((ii0 & 63) == 0) local = readlane_u64(removed, g);  // group resync
                unsigned long long gemask = (lane >= g) ? ~0ull : 0ull;
#pragma unroll
                for (int k2 = 0; k2 < 8; ++k2) {
                    bool keptb = ((local >> ((ii0 & 63) + k2)) & 1ull) == 0ull;  // uniform
                    unsigned long long sel = keptb ? ~0ull : 0ull;
                    removed |= rv[k2] & sel & gemask;  // low words of row are garbage: gemask
                    local |= rg[k2] & sel;             // word g of row: bits<=row are 0
                    keptcnt += keptb ? 1 : 0;
                }
            };

            loadw(rvA, rgA, 0);
            for (int w0 = 0; w0 < nrows; w0 += 16) {
                if (w0 + 8 < nrows) loadw(rvB, rgB, w0 + 8);
                procw(rvA, rgA, w0);
                if (w0 + 8 < nrows) {
                    if (w0 + 16 < nrows) loadw(rvA, rgA, w0 + 16);
                    procw(rvB, rgB, w0 + 8);
                }
            }
            if (keptcnt >= PK && c + 1 < nchunks) {
                // rows beyond this chunk can't reach the output: mark suppressed
                if (lane >= (c + 1) * (SCH / 64)) removed = ~0ull;
                if (lane == 0) stopflag = 1;
            }
        }
        __syncthreads();
        if (stopflag) break;
    }
    if (wv == 0 && lane < W) {
        int remn = K - lane * 64;
        unsigned long long valid = (remn >= 64) ? ~0ull : ((1ull << remn) - 1ull);
        kept[bl * MASKW + lane] = (~removed) & valid;
    }
}

// ---------------- 7) per-level output: compact kept, zero-pad, concat ----------------
__global__ void k_lvlout(const unsigned long long* __restrict__ kept,
                         const float* __restrict__ sels, const float4* __restrict__ selb,
                         float* __restrict__ cscores, float4* __restrict__ cboxes) {
    int bl = blockIdx.x;
    int b = bl / NL, li = bl % NL;
    int K = PREK[li];
    int W = (K + 63) >> 6;
    int PK = POSTK[li];
    int tid = threadIdx.x;  // 256
    __shared__ unsigned long long kw[32];
    __shared__ int pref[33];
    if (tid < W) kw[tid] = kept[bl * MASKW + tid];
    __syncthreads();
    if (tid == 0) {
        int run = 0;
        for (int w = 0; w < W; ++w) { pref[w] = run; run += __popcll(kw[w]); }
        pref[W] = run;
    }
    __syncthreads();
    int total = pref[W];
    int nused = min(total, PK);
    float* cs = cscores + (size_t)b * CONCATN + COFF[li];
    float4* cbx = cboxes + (size_t)b * CONCATN + COFF[li];
    if (tid < W) {
        int rank = pref[tid];
        unsigned long long w64 = kw[tid];
        while (w64 != 0ull && rank < PK) {
            int j = __ffsll(w64) - 1;
            w64 &= (w64 - 1);
            int pidx = tid * 64 + j;
            cs[rank] = sels[(size_t)bl * SELSTRIDE + pidx];
            cbx[rank] = selb[(size_t)bl * SELSTRIDE + pidx];
            ++rank;
        }
    }
    for (int r = nused + tid; r < PK; r += 256) {
        cs[r] = 0.f;
        cbx[r] = make_float4(0.f, 0.f, 0.f, 0.f);
    }
}

// ---------------- 8) final per-batch top-1000: rank 5 sorted runs by counting ----------------
// cscores per batch = 5 strictly-descending runs (kept entries sorted by key;
// zero-pads have keys (0,~idx) also descending). Element i's global rank =
// own-run index + sum over other runs of count-greater (binary search in LDS).
// rank < 1000 scatters straight to the output. Same unique u64 keys as the old
// bitonic -> identical tie semantics, no sort needed.
__global__ __launch_bounds__(1024) void k_final(const float* __restrict__ cscores,
                                                const float4* __restrict__ cboxes,
                                                float* __restrict__ out) {
    __shared__ unsigned long long keys[CONCATN];
    int b = blockIdx.x;
    int tid = threadIdx.x;
    const float* cs = cscores + (size_t)b * CONCATN;
    for (int i = tid; i < CONCATN; i += 1024)
        keys[i] = (((unsigned long long)__float_as_uint(cs[i]) << 32) |
                   (unsigned long long)(0xFFFFFFFFu - (unsigned int)i));
    __syncthreads();
    const float4* cbx = cboxes + (size_t)b * CONCATN;
    float4* ob = reinterpret_cast<float4*>(out) + (size_t)b * 1000;
    float* os = out + (size_t)BATCH * 1000 * 4 + (size_t)b * 1000;
    for (int i = tid; i < CONCATN; i += 1024) {
        unsigned long long k = keys[i];
        int myli = min(i / 1000, 4);
        int rank = i - COFF[myli];  // own run strictly desc -> own index = count-greater
#pragma unroll
        for (int r = 0; r < NL; ++r) {
            if (r == myli) continue;
            const unsigned long long* run = keys + COFF[r];
            int lo = 0, hi = POSTK[r];
            while (lo < hi) {  // count of elements > k in a descending run
                int mid = (lo + hi) >> 1;
                if (run[mid] > k) lo = mid + 1; else hi = mid;
            }
            rank += lo;
        }
        if (rank < 1000) {
            ob[rank] = cbx[i];
            os[rank] = __uint_as_float((unsigned int)(k >> 32));
        }
    }
}

// ---------------- launcher ----------------
extern "C" void kernel_launch(void* const* d_in, const int* in_sizes, int n_in,
                              void* d_out, int out_size, void* d_ws, size_t ws_size,
                              hipStream_t stream) {
    Ptrs p;
    // setup_inputs() dict order: (boxes,scores,anchors) per level, then image_shape.
    bool dict_order = (in_sizes[2] == 6291456);
    for (int l = 0; l < 5; ++l) {
        if (dict_order) {
            p.bx[l] = (const float*)d_in[3 * l + 0];
            p.sc[l] = (const float*)d_in[3 * l + 1];
            p.an[l] = (const float*)d_in[3 * l + 2];
        } else {
            p.bx[l] = (const float*)d_in[l];
            p.sc[l] = (const float*)d_in[5 + l];
            p.an[l] = (const float*)d_in[10 + l];
        }
    }
    p.img = (const float*)d_in[15];

    char* ws = (char*)d_ws;
    size_t off = 0;
    auto walloc = [&](size_t sz) -> void* {
        void* r = ws + off;
        off = (off + sz + 255) & ~(size_t)255;
        return r;
    };
    unsigned int* hist         = (unsigned int*)walloc((size_t)40 * NBINS * 4);
    unsigned int* cntR         = (unsigned int*)walloc((size_t)NREP * 64 * 4);
    int* T                     = (int*)walloc(40 * 4);
    unsigned long long* cand   = (unsigned long long*)walloc((size_t)40 * NREP * REPCAP * 8);
    float4* selb               = (float4*)walloc((size_t)40 * SELSTRIDE * 16);
    float* sels                = (float*)walloc((size_t)40 * SELSTRIDE * 4);
    unsigned long long* mask   = (unsigned long long*)walloc((size_t)40 * MASKROWS * MASKW * 8);
    unsigned long long* kept   = (unsigned long long*)walloc((size_t)40 * MASKW * 8);
    float* cscores             = (float*)walloc((size_t)BATCH * CONCATN * 4);
    float4* cboxes             = (float4*)walloc((size_t)BATCH * CONCATN * 16);
    (void)ws_size;

    hipMemsetAsync(hist, 0, (size_t)40 * NBINS * 4, stream);
    hipMemsetAsync(cntR, 0, (size_t)NREP * 64 * 4, stream);

    k_hist<<<BATCH * 11, 1024, 0, stream>>>(p, hist);
    k_findbin<<<40, 256, 0, stream>>>(hist, T);
    k_compact<<<(TOTC + 255) / 256, 256, 0, stream>>>(p, T, cand, cntR);
    k_sortsel<<<40, 1024, 0, stream>>>(cand, cntR, p, selb, sels);
    k_mask<<<BATCH * ROWS_PER_BATCH, 256, 0, stream>>>(selb, mask);
    k_scan<<<40, 256, 0, stream>>>(mask, kept);
    k_lvlout<<<40, 256, 0, stream>>>(kept, sels, selb, cscores, cboxes);
    k_final<<<8, 1024, 0, stream>>>(cscores, cboxes, (float*)d_out);
}